// Round 4
// baseline (223.941 us; speedup 1.0000x reference)
//
#include <hip/hip_runtime.h>
#include <math.h>

// SpaTrans on MI355X. R4: 7-launch pipeline. Transposed-MFMA GEMMs (weights=M,
// tokens=N) so GEMM chains fuse via the C-frag==B-frag permutation trick
// (verified in R3 k_attn). k_ffn = ff1+relu+ff2+residual+conv in one kernel.
#define Lh 32
#define Lw 32
#define LL 1024
#define BN 25
#define EE 128
#define CC 64
#define NHD 8
#define DH 16
#define FFD 256
#define MROWS 25600

typedef __attribute__((ext_vector_type(8))) short short8;
typedef __attribute__((ext_vector_type(4))) float f32x4;

__device__ inline ushort f2b(float x) {
    union { float f; unsigned u; } v; v.f = x;
    unsigned r = (v.u + 0x7fffu + ((v.u >> 16) & 1u)) >> 16;
    return (ushort)r;
}

// ---------------------------------------------------------------------------
// Weight prep. W2 (w_mlp) K-reordered (k'=tap*64+ch). W2F and WC columns are
// PERMUTED so the previous stage's C-frag can be packed directly as the
// B-operand: k-slot kpos=c*32+quad*8+i  <->  orig k=(2c+(i>>2))*16+quad*4+(i&3)
// ---------------------------------------------------------------------------
#define OFF_W2  0
#define OFF_WQK 73728
#define OFF_WV  106496
#define OFF_WO  122880
#define OFF_W1  139264
#define OFF_W2F 172032
#define OFF_WC  204800
#define W_TOTAL 212992

__global__ __launch_bounds__(256) void k_prep_w(
    const float* __restrict__ w_mlp, const float* __restrict__ in_proj,
    const float* __restrict__ out_proj, const float* __restrict__ ff_w1,
    const float* __restrict__ ff_w2, const float* __restrict__ conv_w,
    ushort* __restrict__ Wb)
{
    int i = blockIdx.x * 256 + threadIdx.x;
    if (i >= W_TOTAL) return;
    if (i < 73728) {
        int e = i / 576, k = i - e * 576;
        int tap = k >> 6, ch = k & 63;
        Wb[OFF_W2 + i] = f2b(w_mlp[e * 576 + ch * 9 + tap]);
        return;
    }
    i -= 73728;
    if (i < 32768) { Wb[OFF_WQK + i] = f2b(in_proj[i]); return; }
    i -= 32768;
    if (i < 16384) { Wb[OFF_WV + i] = f2b(in_proj[32768 + i]); return; }
    i -= 16384;
    if (i < 16384) { Wb[OFF_WO + i] = f2b(out_proj[i]); return; }
    i -= 16384;
    if (i < 32768) { Wb[OFF_W1 + i] = f2b(ff_w1[i]); return; }
    i -= 32768;
    if (i < 32768) {   // W2F, k-permuted (K=256, c=0..7)
        int e = i >> 8, kpos = i & 255;
        int c = kpos >> 5, q = (kpos >> 3) & 3, ii = kpos & 7;
        int orig = (2 * c + (ii >> 2)) * 16 + q * 4 + (ii & 3);
        Wb[OFF_W2F + i] = f2b(ff_w2[e * 256 + orig]);
        return;
    }
    i -= 32768;
    {                  // WC, k-permuted (K=128, c=0..3)
        int o = i >> 7, kpos = i & 127;
        int c = kpos >> 5, q = (kpos >> 3) & 3, ii = kpos & 7;
        int orig = (2 * c + (ii >> 2)) * 16 + q * 4 + (ii & 3);
        Wb[OFF_WC + i] = f2b(conv_w[o * 128 + orig]);
    }
}

// ---------------------------------------------------------------------------
// Input prep: buf [ch][n][y][x] fp32 -> T [n][y][x][ch] bf16, S = bf16(buf+spa)
// ---------------------------------------------------------------------------
__global__ __launch_bounds__(256) void k_prep_in(
    const float* __restrict__ buf, const float* __restrict__ spa,
    ushort* __restrict__ T, ushort* __restrict__ S)
{
    const int n = blockIdx.x, y = blockIdx.y;
    __shared__ float t0[64][33];
    __shared__ float t1[64][33];
    const int t = threadIdx.x;
    {
        int ch = t >> 2, x8 = (t & 3) * 8;
        const float* p = buf + ((size_t)(ch * BN + n) * LL + y * Lw + x8);
        const float* q = spa + ((size_t)(ch * BN + n) * LL + y * Lw + x8);
        float4 a0 = ((const float4*)p)[0], a1 = ((const float4*)p)[1];
        float4 b0 = ((const float4*)q)[0], b1 = ((const float4*)q)[1];
        float* d0 = &t0[ch][x8];
        float* d1 = &t1[ch][x8];
        d0[0] = a0.x; d0[1] = a0.y; d0[2] = a0.z; d0[3] = a0.w;
        d0[4] = a1.x; d0[5] = a1.y; d0[6] = a1.z; d0[7] = a1.w;
        d1[0] = a0.x + b0.x; d1[1] = a0.y + b0.y; d1[2] = a0.z + b0.z; d1[3] = a0.w + b0.w;
        d1[4] = a1.x + b1.x; d1[5] = a1.y + b1.y; d1[6] = a1.z + b1.z; d1[7] = a1.w + b1.w;
    }
    __syncthreads();
    {
        int x = t >> 3, c8 = (t & 7) * 8;
        union { ushort u[8]; uint4 v; } o0, o1;
#pragma unroll
        for (int j = 0; j < 8; j++) { o0.u[j] = f2b(t0[c8 + j][x]); o1.u[j] = f2b(t1[c8 + j][x]); }
        size_t base = (((size_t)n * Lh + y) * Lw + x) * 64 + c8;
        *(uint4*)(T + base) = o0.v;
        *(uint4*)(S + base) = o1.v;
    }
}

// ---------------------------------------------------------------------------
// Token embed via MFMA + fused LN1 (unchanged from R3).
// ---------------------------------------------------------------------------
__global__ __launch_bounds__(256) void k_token_mfma(
    const ushort* __restrict__ T, const ushort* __restrict__ S,
    const ushort* __restrict__ W2, const float* __restrict__ g1,
    const float* __restrict__ b1, float* __restrict__ tok,
    ushort* __restrict__ XLN)
{
    const int n = blockIdx.x, y = blockIdx.y;
    __shared__ ushort At[3 * 34 * 72];
    __shared__ ushort As_[3 * 34 * 72];
    __shared__ float2 red[32][4];
    const int t = threadIdx.x;
    const uint4 z = make_uint4(0, 0, 0, 0);

    {
        int x = t >> 3, c8 = (t & 7) * 8;
#pragma unroll
        for (int dy = 0; dy < 3; dy++) {
            int yy = y + dy - 1;
            uint4 va = z, vs = z;
            if (yy >= 0 && yy < Lh) {
                size_t gi = (((size_t)n * Lh + yy) * Lw + x) * 64 + c8;
                va = *(const uint4*)(T + gi);
                vs = *(const uint4*)(S + gi);
            }
            *(uint4*)(At + (dy * 34 + x + 1) * 72 + c8) = va;
            *(uint4*)(As_ + (dy * 34 + x + 1) * 72 + c8) = vs;
        }
        if (t < 48) {
            int dy = t / 16, rem = t % 16;
            int colp = (rem >> 3) * 33, c8p = (rem & 7) * 8;
            *(uint4*)(At + (dy * 34 + colp) * 72 + c8p) = z;
            *(uint4*)(As_ + (dy * 34 + colp) * 72 + c8p) = z;
        }
    }
    __syncthreads();

    const int w = t >> 6, lane = t & 63;
    const int col = lane & 15, quad = lane >> 4;
    f32x4 accT[2][2] = {}, accS[2][2] = {};

    for (int tap = 0; tap < 9; tap++) {
        int dy = tap / 3, dx = tap % 3;
#pragma unroll
        for (int cc = 0; cc < 2; cc++) {
            int kg = tap * 64 + cc * 32 + quad * 8;
            short8 b0 = *(const short8*)(W2 + (size_t)(w * 32 + col) * 576 + kg);
            short8 bq = *(const short8*)(W2 + (size_t)(w * 32 + 16 + col) * 576 + kg);
            int abase = (dy * 34 + col + dx) * 72 + cc * 32 + quad * 8;
            short8 aT0 = *(const short8*)(At + abase);
            short8 aT1 = *(const short8*)(At + abase + 16 * 72);
            short8 aS0 = *(const short8*)(As_ + abase);
            short8 aS1 = *(const short8*)(As_ + abase + 16 * 72);
            accT[0][0] = __builtin_amdgcn_mfma_f32_16x16x32_bf16(aT0, b0, accT[0][0], 0, 0, 0);
            accT[0][1] = __builtin_amdgcn_mfma_f32_16x16x32_bf16(aT0, bq, accT[0][1], 0, 0, 0);
            accT[1][0] = __builtin_amdgcn_mfma_f32_16x16x32_bf16(aT1, b0, accT[1][0], 0, 0, 0);
            accT[1][1] = __builtin_amdgcn_mfma_f32_16x16x32_bf16(aT1, bq, accT[1][1], 0, 0, 0);
            accS[0][0] = __builtin_amdgcn_mfma_f32_16x16x32_bf16(aS0, b0, accS[0][0], 0, 0, 0);
            accS[0][1] = __builtin_amdgcn_mfma_f32_16x16x32_bf16(aS0, bq, accS[0][1], 0, 0, 0);
            accS[1][0] = __builtin_amdgcn_mfma_f32_16x16x32_bf16(aS1, b0, accS[1][0], 0, 0, 0);
            accS[1][1] = __builtin_amdgcn_mfma_f32_16x16x32_bf16(aS1, bq, accS[1][1], 0, 0, 0);
        }
    }

#pragma unroll
    for (int mi = 0; mi < 2; mi++)
#pragma unroll
        for (int r = 0; r < 4; r++) {
            float a0 = accS[mi][0][r], a1 = accS[mi][1][r];
            float ss = a0 + a1, qq = a0 * a0 + a1 * a1;
#pragma unroll
            for (int m = 1; m < 16; m <<= 1) {
                ss += __shfl_xor(ss, m, 64);
                qq += __shfl_xor(qq, m, 64);
            }
            if (col == 0) red[mi * 16 + quad * 4 + r][w] = make_float2(ss, qq);
        }
    __syncthreads();

    const float ga = g1[w * 32 + col],      ba = b1[w * 32 + col];
    const float gb = g1[w * 32 + 16 + col], bb = b1[w * 32 + 16 + col];
#pragma unroll
    for (int mi = 0; mi < 2; mi++)
#pragma unroll
        for (int r = 0; r < 4; r++) {
            int x = mi * 16 + quad * 4 + r;
            float2 p0 = red[x][0], p1 = red[x][1], p2 = red[x][2], p3 = red[x][3];
            float mean = (p0.x + p1.x + p2.x + p3.x) * (1.f / 128.f);
            float var  = (p0.y + p1.y + p2.y + p3.y) * (1.f / 128.f) - mean * mean;
            float rstd = rsqrtf(var + 1e-5f);
            size_t rowo = ((size_t)(y * Lw + x) * BN + n) * EE;
            int e0 = w * 32 + col, e1 = w * 32 + 16 + col;
            tok[rowo + e0] = accT[mi][0][r];
            tok[rowo + e1] = accT[mi][1][r];
            XLN[rowo + e0] = f2b((accS[mi][0][r] - mean) * rstd * ga + ba);
            XLN[rowo + e1] = f2b((accS[mi][1][r] - mean) * rstd * gb + bb);
        }
}

// ---------------------------------------------------------------------------
// Fused QKV. Block = 64 l-major rows (bn fixed). Transposed GEMM: A=weights
// (M=e), B=token rows from LDS (N=token). Stores [n][h][l][d] coalesced.
// ---------------------------------------------------------------------------
__global__ __launch_bounds__(256) void k_qkv(
    const ushort* __restrict__ XLN, const float* __restrict__ TOK,
    const ushort* __restrict__ WQK, const ushort* __restrict__ WV,
    ushort* __restrict__ Qh, ushort* __restrict__ Kh, ushort* __restrict__ Vh)
{
    __shared__ ushort As[64 * 130];
    __shared__ ushort Vs[64 * 130];
    const int b = blockIdx.x, bn = b % 25, l0 = (b / 25) * 64;
    const int t = threadIdx.x, w = t >> 6, lane = t & 63;
    const int col = lane & 15, quad = lane >> 4;

    {
        int r = t >> 2, seg = t & 3;
        size_t m = (size_t)(l0 + r) * 25 + bn;
        const uint4* px = (const uint4*)(XLN + m * 128 + seg * 32);
        *(uint4*)(As + r * 130 + seg * 32)      = px[0];
        *(uint4*)(As + r * 130 + seg * 32 + 8)  = px[1];
        *(uint4*)(As + r * 130 + seg * 32 + 16) = px[2];
        *(uint4*)(As + r * 130 + seg * 32 + 24) = px[3];
        const float4* pt = (const float4*)(TOK + m * 128 + seg * 32);
#pragma unroll
        for (int j = 0; j < 4; j++) {
            float4 f0 = pt[2 * j], f1 = pt[2 * j + 1];
            union { ushort u[8]; uint4 v; } o;
            o.u[0] = f2b(f0.x); o.u[1] = f2b(f0.y); o.u[2] = f2b(f0.z); o.u[3] = f2b(f0.w);
            o.u[4] = f2b(f1.x); o.u[5] = f2b(f1.y); o.u[6] = f2b(f1.z); o.u[7] = f2b(f1.w);
            *(uint4*)(Vs + r * 130 + seg * 32 + j * 8) = o.v;
        }
    }
    __syncthreads();

    short8 xb[4], xv[4];
#pragma unroll
    for (int kc = 0; kc < 4; kc++) {
        xb[kc] = *(const short8*)(As + (w * 16 + col) * 130 + kc * 32 + quad * 8);
        xv[kc] = *(const short8*)(Vs + (w * 16 + col) * 130 + kc * 32 + quad * 8);
    }
    f32x4 Q[8] = {}, K[8] = {}, V[8] = {};
#pragma unroll
    for (int et = 0; et < 8; et++)
#pragma unroll
        for (int kc = 0; kc < 4; kc++) {
            short8 aq = *(const short8*)(WQK + (size_t)(et * 16 + col) * 128 + kc * 32 + quad * 8);
            short8 ak = *(const short8*)(WQK + (size_t)(128 + et * 16 + col) * 128 + kc * 32 + quad * 8);
            short8 av = *(const short8*)(WV + (size_t)(et * 16 + col) * 128 + kc * 32 + quad * 8);
            Q[et] = __builtin_amdgcn_mfma_f32_16x16x32_bf16(aq, xb[kc], Q[et], 0, 0, 0);
            K[et] = __builtin_amdgcn_mfma_f32_16x16x32_bf16(ak, xb[kc], K[et], 0, 0, 0);
            V[et] = __builtin_amdgcn_mfma_f32_16x16x32_bf16(av, xv[kc], V[et], 0, 0, 0);
        }

    // store: head = et (DH=16), d = quad*4+r, l = l0+w*16+col
    const int l = l0 + w * 16 + col;
#pragma unroll
    for (int et = 0; et < 8; et++) {
        size_t base = ((size_t)(bn * 8 + et) * 1024 + l) * 16 + quad * 4;
        ushort4 oq, ok, ov;
        oq.x = f2b(Q[et][0]); oq.y = f2b(Q[et][1]); oq.z = f2b(Q[et][2]); oq.w = f2b(Q[et][3]);
        ok.x = f2b(K[et][0]); ok.y = f2b(K[et][1]); ok.z = f2b(K[et][2]); ok.w = f2b(K[et][3]);
        ov.x = f2b(V[et][0]); ov.y = f2b(V[et][1]); ov.z = f2b(V[et][2]); ov.w = f2b(V[et][3]);
        *(ushort4*)(Qh + base) = oq;
        *(ushort4*)(Kh + base) = ok;
        *(ushort4*)(Vh + base) = ov;
    }
}

// ---------------------------------------------------------------------------
// MFMA local-window attention (unchanged from R3).
// ---------------------------------------------------------------------------
__global__ __launch_bounds__(256) void k_attn(
    const ushort* __restrict__ Qh, const ushort* __restrict__ Kh,
    const ushort* __restrict__ Vh, ushort* __restrict__ AO)
{
    __shared__ ushort VT[4][16 * 168];
    const int t = threadIdx.x, w = t >> 6, lane = t & 63;
    const int col = lane & 15, quad = lane >> 4;
    const int wid = blockIdx.x * 4 + w;
    const int y = wid & 31, h = (wid >> 5) & 7, n = wid >> 8;
    const size_t base = (size_t)(n * 8 + h) * 1024;

    for (int i = lane; i < 160; i += 64) {
        int kr = i >> 5, kx = i & 31;
        int yyc = min(max(y - 2 + kr, 0), 31);
        const ushort* src = Vh + (base + yyc * 32 + kx) * 16;
        union { uint4 v; ushort u[8]; } ua, ub;
        ua.v = *(const uint4*)(src);
        ub.v = *(const uint4*)(src + 8);
        int pos = (kr << 5) + (((kx & 15) >> 2) << 3) + ((kx >> 4) << 2) + (kx & 3);
        ushort* dst = &VT[w][pos];
#pragma unroll
        for (int d = 0; d < 8; d++) dst[d * 168] = ua.u[d];
#pragma unroll
        for (int d = 0; d < 8; d++) dst[(d + 8) * 168] = ub.u[d];
    }

    short8 z8 = {0, 0, 0, 0, 0, 0, 0, 0};
    short8 qf[2] = { z8, z8 };
#pragma unroll
    for (int j = 0; j < 2; j++)
        if (quad < 2)
            qf[j] = *(const short8*)(Qh + (base + y * 32 + j * 16 + col) * 16 + quad * 8);

    f32x4 S[2][10] = {};
#pragma unroll
    for (int tt = 0; tt < 10; tt++) {
        int kr = tt >> 1, kx = ((tt & 1) << 4) + col;
        int yyc = min(max(y - 2 + kr, 0), 31);
        short8 kf = z8;
        if (quad < 2)
            kf = *(const short8*)(Kh + (base + yyc * 32 + kx) * 16 + quad * 8);
        S[0][tt] = __builtin_amdgcn_mfma_f32_16x16x32_bf16(kf, qf[0], S[0][tt], 0, 0, 0);
        S[1][tt] = __builtin_amdgcn_mfma_f32_16x16x32_bf16(kf, qf[1], S[1][tt], 0, 0, 0);
    }

    float invs[2];
#pragma unroll
    for (int j = 0; j < 2; j++) {
        int qx = j * 16 + col;
        float mx = -1e30f;
#pragma unroll
        for (int tt = 0; tt < 10; tt++) {
            int yy = y - 2 + (tt >> 1);
            bool rok = (yy >= 0) && (yy < 32);
            int kxb = ((tt & 1) << 4) + quad * 4;
#pragma unroll
            for (int r = 0; r < 4; r++) {
                int dd = kxb + r - qx;
                bool ok = rok && ((unsigned)(dd + 2) <= 4u);
                float v = ok ? S[j][tt][r] * 0.25f : -1e30f;
                S[j][tt][r] = v;
                mx = fmaxf(mx, v);
            }
        }
        mx = fmaxf(mx, __shfl_xor(mx, 16, 64));
        mx = fmaxf(mx, __shfl_xor(mx, 32, 64));
        float sum = 0.f;
#pragma unroll
        for (int tt = 0; tt < 10; tt++)
#pragma unroll
            for (int r = 0; r < 4; r++) {
                float p = __expf(S[j][tt][r] - mx);
                S[j][tt][r] = p;
                sum += p;
            }
        sum += __shfl_xor(sum, 16, 64);
        sum += __shfl_xor(sum, 32, 64);
        invs[j] = 1.f / sum;
    }

    f32x4 O[2] = {};
#pragma unroll
    for (int c = 0; c < 5; c++) {
        short8 vt = *(const short8*)(&VT[w][col * 168 + c * 32 + quad * 8]);
#pragma unroll
        for (int j = 0; j < 2; j++) {
            union { ushort u[8]; short8 s; } pb;
#pragma unroll
            for (int i = 0; i < 8; i++)
                pb.u[i] = f2b(S[j][2 * c + (i >> 2)][i & 3] * invs[j]);
            O[j] = __builtin_amdgcn_mfma_f32_16x16x32_bf16(vt, pb.s, O[j], 0, 0, 0);
        }
    }

#pragma unroll
    for (int j = 0; j < 2; j++) {
        int l = y * Lw + j * 16 + col;
        ushort4 o;
        o.x = f2b(O[j][0]); o.y = f2b(O[j][1]); o.z = f2b(O[j][2]); o.w = f2b(O[j][3]);
        *(ushort4*)(AO + ((size_t)l * BN + n) * EE + h * DH + quad * 4) = o;
    }
}

// ---------------------------------------------------------------------------
// out_proj + residual + LN2 fused. Block = 64 m-major rows.
// C-frag col=token: LN over e = in-lane(32 vals) + shfl_xor 16,32.
// Outputs written via LDS transpose for coalescing.
// ---------------------------------------------------------------------------
__global__ __launch_bounds__(256) void k_oln(
    const ushort* __restrict__ AO, const ushort* __restrict__ WO,
    const float* __restrict__ g2, const float* __restrict__ b2,
    float* __restrict__ TOK, ushort* __restrict__ XLN2)
{
    __shared__ ushort As[64 * 130];
    __shared__ float  Rs[64 * 133];
    const int m0 = blockIdx.x * 64;
    const int t = threadIdx.x, w = t >> 6, lane = t & 63;
    const int col = lane & 15, quad = lane >> 4;

    {
        int r = t >> 2, seg = t & 3;
        const uint4* pa = (const uint4*)(AO + (size_t)(m0 + r) * 128 + seg * 32);
        *(uint4*)(As + r * 130 + seg * 32)      = pa[0];
        *(uint4*)(As + r * 130 + seg * 32 + 8)  = pa[1];
        *(uint4*)(As + r * 130 + seg * 32 + 16) = pa[2];
        *(uint4*)(As + r * 130 + seg * 32 + 24) = pa[3];
        const float4* pt = (const float4*)(TOK + (size_t)(m0 + r) * 128 + seg * 32);
#pragma unroll
        for (int j = 0; j < 8; j++)
            *(float4*)(Rs + r * 133 + seg * 32 + j * 4) = pt[j];
    }
    __syncthreads();

    short8 xb[4];
#pragma unroll
    for (int kc = 0; kc < 4; kc++)
        xb[kc] = *(const short8*)(As + (w * 16 + col) * 130 + kc * 32 + quad * 8);

    f32x4 Y[8] = {};
#pragma unroll
    for (int et = 0; et < 8; et++)
#pragma unroll
        for (int kc = 0; kc < 4; kc++) {
            short8 a = *(const short8*)(WO + (size_t)(et * 16 + col) * 128 + kc * 32 + quad * 8);
            Y[et] = __builtin_amdgcn_mfma_f32_16x16x32_bf16(a, xb[kc], Y[et], 0, 0, 0);
        }

    // residual + LN stats (token = w*16+col)
    float s = 0.f, q = 0.f;
#pragma unroll
    for (int et = 0; et < 8; et++)
#pragma unroll
        for (int r = 0; r < 4; r++) {
            float v = Y[et][r] + Rs[(w * 16 + col) * 133 + et * 16 + quad * 4 + r];
            Y[et][r] = v;
            s += v; q += v * v;
        }
    s += __shfl_xor(s, 16, 64); s += __shfl_xor(s, 32, 64);
    q += __shfl_xor(q, 16, 64); q += __shfl_xor(q, 32, 64);
    float mean = s * (1.f / 128.f);
    float var  = q * (1.f / 128.f) - mean * mean;
    float rstd = rsqrtf(var + 1e-5f);

    // write transposed into LDS
#pragma unroll
    for (int et = 0; et < 8; et++)
#pragma unroll
        for (int r = 0; r < 4; r++) {
            int e = et * 16 + quad * 4 + r;
            float v = Y[et][r];
            Rs[(w * 16 + col) * 133 + e] = v;
            As[(w * 16 + col) * 130 + e] = f2b((v - mean) * rstd * g2[e] + b2[e]);
        }
    __syncthreads();

    {
        int r = t >> 2, seg = t & 3;
        size_t m = (size_t)(m0 + r);
#pragma unroll
        for (int j = 0; j < 8; j++)
            *(float4*)(TOK + m * 128 + seg * 32 + j * 4) = *(const float4*)(Rs + r * 133 + seg * 32 + j * 4);
        uint4* dx = (uint4*)(XLN2 + m * 128 + seg * 32);
        dx[0] = *(const uint4*)(As + r * 130 + seg * 32);
        dx[1] = *(const uint4*)(As + r * 130 + seg * 32 + 8);
        dx[2] = *(const uint4*)(As + r * 130 + seg * 32 + 16);
        dx[3] = *(const uint4*)(As + r * 130 + seg * 32 + 24);
    }
}

// ---------------------------------------------------------------------------
// Mega-fused FFN: ff1 + relu + ff2 + residual + conv + output scatter.
// Block = 64 l-major rows (bn fixed). Stage1 C-frags become stage2 B-frags
// via pre-permuted W2P; same again for conv (WCP). Writes d_out coalesced.
// ---------------------------------------------------------------------------
__global__ __launch_bounds__(256) void k_ffn(
    const ushort* __restrict__ XLN2, const float* __restrict__ TOK,
    const ushort* __restrict__ W1, const ushort* __restrict__ W2P,
    const ushort* __restrict__ WCP, float* __restrict__ out)
{
    __shared__ ushort As[64 * 130];
    __shared__ float  Rs[64 * 133];
    const int b = blockIdx.x, bn = b % 25, l0 = (b / 25) * 64;
    const int t = threadIdx.x, w = t >> 6, lane = t & 63;
    const int col = lane & 15, quad = lane >> 4;

    {
        int r = t >> 2, seg = t & 3;
        size_t m = (size_t)(l0 + r) * 25 + bn;
        const uint4* px = (const uint4*)(XLN2 + m * 128 + seg * 32);
        *(uint4*)(As + r * 130 + seg * 32)      = px[0];
        *(uint4*)(As + r * 130 + seg * 32 + 8)  = px[1];
        *(uint4*)(As + r * 130 + seg * 32 + 16) = px[2];
        *(uint4*)(As + r * 130 + seg * 32 + 24) = px[3];
        const float4* pt = (const float4*)(TOK + m * 128 + seg * 32);
#pragma unroll
        for (int j = 0; j < 8; j++)
            *(float4*)(Rs + r * 133 + seg * 32 + j * 4) = pt[j];
    }
    __syncthreads();

    short8 xb[4];
#pragma unroll
    for (int kc = 0; kc < 4; kc++)
        xb[kc] = *(const short8*)(As + (w * 16 + col) * 130 + kc * 32 + quad * 8);

    // phase 1: H^T = W1 · X^T  (16 ff-tiles)
    f32x4 H[16] = {};
#pragma unroll
    for (int ft = 0; ft < 16; ft++)
#pragma unroll
        for (int kc = 0; kc < 4; kc++) {
            short8 a = *(const short8*)(W1 + (size_t)(ft * 16 + col) * 128 + kc * 32 + quad * 8);
            H[ft] = __builtin_amdgcn_mfma_f32_16x16x32_bf16(a, xb[kc], H[ft], 0, 0, 0);
        }

    // phase 2: Y^T = W2P · relu(H)  (C-frag pairs packed as B-operand)
    f32x4 Y[8] = {};
#pragma unroll
    for (int c = 0; c < 8; c++) {
        union { ushort u[8]; short8 s; } pb;
#pragma unroll
        for (int i = 0; i < 8; i++)
            pb.u[i] = f2b(fmaxf(H[2 * c + (i >> 2)][i & 3], 0.f));
#pragma unroll
        for (int et = 0; et < 8; et++) {
            short8 a = *(const short8*)(W2P + (size_t)(et * 16 + col) * 256 + c * 32 + quad * 8);
            Y[et] = __builtin_amdgcn_mfma_f32_16x16x32_bf16(a, pb.s, Y[et], 0, 0, 0);
        }
    }

    // residual (token = w*16+col, e = et*16+quad*4+r)
#pragma unroll
    for (int et = 0; et < 8; et++)
#pragma unroll
        for (int r = 0; r < 4; r++)
            Y[et][r] += Rs[(w * 16 + col) * 133 + et * 16 + quad * 4 + r];

    // phase 3: conv: O = WCP · pack(Y)
    f32x4 O[4] = {};
#pragma unroll
    for (int c = 0; c < 4; c++) {
        union { ushort u[8]; short8 s; } pb;
#pragma unroll
        for (int i = 0; i < 8; i++)
            pb.u[i] = f2b(Y[2 * c + (i >> 2)][i & 3]);
#pragma unroll
        for (int ot = 0; ot < 4; ot++) {
            short8 a = *(const short8*)(WCP + (size_t)(ot * 16 + col) * 128 + c * 32 + quad * 8);
            O[ot] = __builtin_amdgcn_mfma_f32_16x16x32_bf16(a, pb.s, O[ot], 0, 0, 0);
        }
    }

    // store out[(o*25+bn)*1024 + l]: 16 lanes -> 64B contiguous per (ot,r)
    const int l = l0 + w * 16 + col;
#pragma unroll
    for (int ot = 0; ot < 4; ot++)
#pragma unroll
        for (int r = 0; r < 4; r++) {
            int o = ot * 16 + quad * 4 + r;
            out[(size_t)(o * 25 + bn) * 1024 + l] = O[ot][r];
        }
}

// ---------------------------------------------------------------------------
// Launch
// ---------------------------------------------------------------------------
extern "C" void kernel_launch(void* const* d_in, const int* in_sizes, int n_in,
                              void* d_out, int out_size, void* d_ws, size_t ws_size,
                              hipStream_t stream)
{
    const float* buffer   = (const float*)d_in[0];
    const float* spa      = (const float*)d_in[1];
    const float* w_mlp    = (const float*)d_in[2];
    const float* ln1_g    = (const float*)d_in[3];
    const float* ln1_b    = (const float*)d_in[4];
    const float* in_proj  = (const float*)d_in[5];
    const float* out_proj = (const float*)d_in[6];
    const float* ln2_g    = (const float*)d_in[7];
    const float* ln2_b    = (const float*)d_in[8];
    const float* ff_w1    = (const float*)d_in[9];
    const float* ff_w2    = (const float*)d_in[10];
    const float* conv_w   = (const float*)d_in[11];
    float* out = (float*)d_out;

    char* ws = (char*)d_ws;
    float*  TOK  = (float*)(ws);                 // 13,107,200 fp32 residual
    ushort* XLN  = (ushort*)(ws + 13107200);     //  6,553,600 ln1 out bf16
    ushort* Qh   = (ushort*)(ws + 19660800);     //  6,553,600 [n][h][l][d]
    ushort* Kh   = (ushort*)(ws + 26214400);     //  6,553,600
    ushort* Vh   = (ushort*)(ws + 32768000);     //  6,553,600
    ushort* AO   = (ushort*)(ws + 39321600);     //  6,553,600 attn out [l][n][e]
    ushort* XLN2 = (ushort*)(ws + 45875200);     //  6,553,600 ln2 out bf16
    ushort* Tbf  = (ushort*)(ws + 52428800);     //  3,276,800
    ushort* Sbf  = (ushort*)(ws + 55705600);     //  3,276,800
    ushort* Wb   = (ushort*)(ws + 58982400);     //    425,984

    k_prep_w<<<dim3((W_TOTAL + 255) / 256), 256, 0, stream>>>(
        w_mlp, in_proj, out_proj, ff_w1, ff_w2, conv_w, Wb);
    k_prep_in<<<dim3(BN, Lh), 256, 0, stream>>>(buffer, spa, Tbf, Sbf);
    k_token_mfma<<<dim3(BN, Lh), 256, 0, stream>>>(Tbf, Sbf, Wb + OFF_W2,
                                                   ln1_g, ln1_b, TOK, XLN);
    k_qkv<<<dim3(400), 256, 0, stream>>>(XLN, TOK, Wb + OFF_WQK, Wb + OFF_WV,
                                         Qh, Kh, Vh);
    k_attn<<<dim3(1600), 256, 0, stream>>>(Qh, Kh, Vh, AO);
    k_oln<<<dim3(400), 256, 0, stream>>>(AO, Wb + OFF_WO, ln2_g, ln2_b, TOK, XLN2);
    k_ffn<<<dim3(400), 256, 0, stream>>>(XLN2, TOK, Wb + OFF_W1, Wb + OFF_W2F,
                                         Wb + OFF_WC, out);
}

// Round 5
// 207.428 us; speedup vs baseline: 1.0796x; 1.0796x over previous
//
#include <hip/hip_runtime.h>
#include <math.h>

// SpaTrans on MI355X. R5: fused kernels restructured to 16-token blocks
// (grid 1600) with output-dim split across the 4 waves + LDS exchange.
// Fixes R4's latency-bound 400-block fused kernels (MfmaUtil 3%, Occ 14%).
#define Lh 32
#define Lw 32
#define LL 1024
#define BN 25
#define EE 128
#define CC 64
#define NHD 8
#define DH 16
#define FFD 256
#define MROWS 25600

typedef __attribute__((ext_vector_type(8))) short short8;
typedef __attribute__((ext_vector_type(4))) float f32x4;

__device__ inline ushort f2b(float x) {
    union { float f; unsigned u; } v; v.f = x;
    unsigned r = (v.u + 0x7fffu + ((v.u >> 16) & 1u)) >> 16;
    return (ushort)r;
}

// ---------------------------------------------------------------------------
// Weight prep. W2 (w_mlp) K-reordered (k'=tap*64+ch). W2F and WC columns are
// PERMUTED so the previous stage's C-frag packs directly as the B-operand:
// kpos=c*32+q*8+i  <->  orig k=(2c+(i>>2))*16+q*4+(i&3)
// ---------------------------------------------------------------------------
#define OFF_W2  0
#define OFF_WQK 73728
#define OFF_WV  106496
#define OFF_WO  122880
#define OFF_W1  139264
#define OFF_W2F 172032
#define OFF_WC  204800
#define W_TOTAL 212992

__global__ __launch_bounds__(256) void k_prep_w(
    const float* __restrict__ w_mlp, const float* __restrict__ in_proj,
    const float* __restrict__ out_proj, const float* __restrict__ ff_w1,
    const float* __restrict__ ff_w2, const float* __restrict__ conv_w,
    ushort* __restrict__ Wb)
{
    int i = blockIdx.x * 256 + threadIdx.x;
    if (i >= W_TOTAL) return;
    if (i < 73728) {
        int e = i / 576, k = i - e * 576;
        int tap = k >> 6, ch = k & 63;
        Wb[OFF_W2 + i] = f2b(w_mlp[e * 576 + ch * 9 + tap]);
        return;
    }
    i -= 73728;
    if (i < 32768) { Wb[OFF_WQK + i] = f2b(in_proj[i]); return; }
    i -= 32768;
    if (i < 16384) { Wb[OFF_WV + i] = f2b(in_proj[32768 + i]); return; }
    i -= 16384;
    if (i < 16384) { Wb[OFF_WO + i] = f2b(out_proj[i]); return; }
    i -= 16384;
    if (i < 32768) { Wb[OFF_W1 + i] = f2b(ff_w1[i]); return; }
    i -= 32768;
    if (i < 32768) {   // W2F, k-permuted (K=256)
        int e = i >> 8, kpos = i & 255;
        int c = kpos >> 5, q = (kpos >> 3) & 3, ii = kpos & 7;
        int orig = (2 * c + (ii >> 2)) * 16 + q * 4 + (ii & 3);
        Wb[OFF_W2F + i] = f2b(ff_w2[e * 256 + orig]);
        return;
    }
    i -= 32768;
    {                  // WC, k-permuted (K=128)
        int o = i >> 7, kpos = i & 127;
        int c = kpos >> 5, q = (kpos >> 3) & 3, ii = kpos & 7;
        int orig = (2 * c + (ii >> 2)) * 16 + q * 4 + (ii & 3);
        Wb[OFF_WC + i] = f2b(conv_w[o * 128 + orig]);
    }
}

// ---------------------------------------------------------------------------
// Input prep (unchanged).
// ---------------------------------------------------------------------------
__global__ __launch_bounds__(256) void k_prep_in(
    const float* __restrict__ buf, const float* __restrict__ spa,
    ushort* __restrict__ T, ushort* __restrict__ S)
{
    const int n = blockIdx.x, y = blockIdx.y;
    __shared__ float t0[64][33];
    __shared__ float t1[64][33];
    const int t = threadIdx.x;
    {
        int ch = t >> 2, x8 = (t & 3) * 8;
        const float* p = buf + ((size_t)(ch * BN + n) * LL + y * Lw + x8);
        const float* q = spa + ((size_t)(ch * BN + n) * LL + y * Lw + x8);
        float4 a0 = ((const float4*)p)[0], a1 = ((const float4*)p)[1];
        float4 b0 = ((const float4*)q)[0], b1 = ((const float4*)q)[1];
        float* d0 = &t0[ch][x8];
        float* d1 = &t1[ch][x8];
        d0[0] = a0.x; d0[1] = a0.y; d0[2] = a0.z; d0[3] = a0.w;
        d0[4] = a1.x; d0[5] = a1.y; d0[6] = a1.z; d0[7] = a1.w;
        d1[0] = a0.x + b0.x; d1[1] = a0.y + b0.y; d1[2] = a0.z + b0.z; d1[3] = a0.w + b0.w;
        d1[4] = a1.x + b1.x; d1[5] = a1.y + b1.y; d1[6] = a1.z + b1.z; d1[7] = a1.w + b1.w;
    }
    __syncthreads();
    {
        int x = t >> 3, c8 = (t & 7) * 8;
        union { ushort u[8]; uint4 v; } o0, o1;
#pragma unroll
        for (int j = 0; j < 8; j++) { o0.u[j] = f2b(t0[c8 + j][x]); o1.u[j] = f2b(t1[c8 + j][x]); }
        size_t base = (((size_t)n * Lh + y) * Lw + x) * 64 + c8;
        *(uint4*)(T + base) = o0.v;
        *(uint4*)(S + base) = o1.v;
    }
}

// ---------------------------------------------------------------------------
// Token embed via MFMA + fused LN1 (unchanged from R3/R4).
// ---------------------------------------------------------------------------
__global__ __launch_bounds__(256) void k_token_mfma(
    const ushort* __restrict__ T, const ushort* __restrict__ S,
    const ushort* __restrict__ W2, const float* __restrict__ g1,
    const float* __restrict__ b1, float* __restrict__ tok,
    ushort* __restrict__ XLN)
{
    const int n = blockIdx.x, y = blockIdx.y;
    __shared__ ushort At[3 * 34 * 72];
    __shared__ ushort As_[3 * 34 * 72];
    __shared__ float2 red[32][4];
    const int t = threadIdx.x;
    const uint4 z = make_uint4(0, 0, 0, 0);

    {
        int x = t >> 3, c8 = (t & 7) * 8;
#pragma unroll
        for (int dy = 0; dy < 3; dy++) {
            int yy = y + dy - 1;
            uint4 va = z, vs = z;
            if (yy >= 0 && yy < Lh) {
                size_t gi = (((size_t)n * Lh + yy) * Lw + x) * 64 + c8;
                va = *(const uint4*)(T + gi);
                vs = *(const uint4*)(S + gi);
            }
            *(uint4*)(At + (dy * 34 + x + 1) * 72 + c8) = va;
            *(uint4*)(As_ + (dy * 34 + x + 1) * 72 + c8) = vs;
        }
        if (t < 48) {
            int dy = t / 16, rem = t % 16;
            int colp = (rem >> 3) * 33, c8p = (rem & 7) * 8;
            *(uint4*)(At + (dy * 34 + colp) * 72 + c8p) = z;
            *(uint4*)(As_ + (dy * 34 + colp) * 72 + c8p) = z;
        }
    }
    __syncthreads();

    const int w = t >> 6, lane = t & 63;
    const int col = lane & 15, quad = lane >> 4;
    f32x4 accT[2][2] = {}, accS[2][2] = {};

    for (int tap = 0; tap < 9; tap++) {
        int dy = tap / 3, dx = tap % 3;
#pragma unroll
        for (int cc = 0; cc < 2; cc++) {
            int kg = tap * 64 + cc * 32 + quad * 8;
            short8 b0 = *(const short8*)(W2 + (size_t)(w * 32 + col) * 576 + kg);
            short8 bq = *(const short8*)(W2 + (size_t)(w * 32 + 16 + col) * 576 + kg);
            int abase = (dy * 34 + col + dx) * 72 + cc * 32 + quad * 8;
            short8 aT0 = *(const short8*)(At + abase);
            short8 aT1 = *(const short8*)(At + abase + 16 * 72);
            short8 aS0 = *(const short8*)(As_ + abase);
            short8 aS1 = *(const short8*)(As_ + abase + 16 * 72);
            accT[0][0] = __builtin_amdgcn_mfma_f32_16x16x32_bf16(aT0, b0, accT[0][0], 0, 0, 0);
            accT[0][1] = __builtin_amdgcn_mfma_f32_16x16x32_bf16(aT0, bq, accT[0][1], 0, 0, 0);
            accT[1][0] = __builtin_amdgcn_mfma_f32_16x16x32_bf16(aT1, b0, accT[1][0], 0, 0, 0);
            accT[1][1] = __builtin_amdgcn_mfma_f32_16x16x32_bf16(aT1, bq, accT[1][1], 0, 0, 0);
            accS[0][0] = __builtin_amdgcn_mfma_f32_16x16x32_bf16(aS0, b0, accS[0][0], 0, 0, 0);
            accS[0][1] = __builtin_amdgcn_mfma_f32_16x16x32_bf16(aS0, bq, accS[0][1], 0, 0, 0);
            accS[1][0] = __builtin_amdgcn_mfma_f32_16x16x32_bf16(aS1, b0, accS[1][0], 0, 0, 0);
            accS[1][1] = __builtin_amdgcn_mfma_f32_16x16x32_bf16(aS1, bq, accS[1][1], 0, 0, 0);
        }
    }

#pragma unroll
    for (int mi = 0; mi < 2; mi++)
#pragma unroll
        for (int r = 0; r < 4; r++) {
            float a0 = accS[mi][0][r], a1 = accS[mi][1][r];
            float ss = a0 + a1, qq = a0 * a0 + a1 * a1;
#pragma unroll
            for (int m = 1; m < 16; m <<= 1) {
                ss += __shfl_xor(ss, m, 64);
                qq += __shfl_xor(qq, m, 64);
            }
            if (col == 0) red[mi * 16 + quad * 4 + r][w] = make_float2(ss, qq);
        }
    __syncthreads();

    const float ga = g1[w * 32 + col],      ba = b1[w * 32 + col];
    const float gb = g1[w * 32 + 16 + col], bb = b1[w * 32 + 16 + col];
#pragma unroll
    for (int mi = 0; mi < 2; mi++)
#pragma unroll
        for (int r = 0; r < 4; r++) {
            int x = mi * 16 + quad * 4 + r;
            float2 p0 = red[x][0], p1 = red[x][1], p2 = red[x][2], p3 = red[x][3];
            float mean = (p0.x + p1.x + p2.x + p3.x) * (1.f / 128.f);
            float var  = (p0.y + p1.y + p2.y + p3.y) * (1.f / 128.f) - mean * mean;
            float rstd = rsqrtf(var + 1e-5f);
            size_t rowo = ((size_t)(y * Lw + x) * BN + n) * EE;
            int e0 = w * 32 + col, e1 = w * 32 + 16 + col;
            tok[rowo + e0] = accT[mi][0][r];
            tok[rowo + e1] = accT[mi][1][r];
            XLN[rowo + e0] = f2b((accS[mi][0][r] - mean) * rstd * ga + ba);
            XLN[rowo + e1] = f2b((accS[mi][1][r] - mean) * rstd * gb + bb);
        }
}

// ---------------------------------------------------------------------------
// Fused QKV, 16-token blocks (grid 1600). Wave w computes heads {2w, 2w+1}
// for Q, K, V (6 tiles x 4 K-chunks = 24 MFMAs). Stores [n][h][l][d].
// ---------------------------------------------------------------------------
__global__ __launch_bounds__(256) void k_qkv(
    const ushort* __restrict__ XLN, const float* __restrict__ TOK,
    const ushort* __restrict__ WQK, const ushort* __restrict__ WV,
    ushort* __restrict__ Qh, ushort* __restrict__ Kh, ushort* __restrict__ Vh)
{
    __shared__ ushort Xs[16 * 136];
    __shared__ ushort Vs[16 * 136];
    const int b = blockIdx.x, bn = b % 25, l0 = (b / 25) * 16;
    const int t = threadIdx.x, w = t >> 6, lane = t & 63;
    const int col = lane & 15, quad = lane >> 4;

    {
        int r = t >> 4, seg = t & 15;
        size_t m = (size_t)(l0 + r) * 25 + bn;
        *(uint4*)(Xs + r * 136 + seg * 8) = *(const uint4*)(XLN + m * 128 + seg * 8);
        const float4* pt = (const float4*)(TOK + m * 128 + seg * 8);
        float4 f0 = pt[0], f1 = pt[1];
        union { ushort u[8]; uint4 v; } o;
        o.u[0] = f2b(f0.x); o.u[1] = f2b(f0.y); o.u[2] = f2b(f0.z); o.u[3] = f2b(f0.w);
        o.u[4] = f2b(f1.x); o.u[5] = f2b(f1.y); o.u[6] = f2b(f1.z); o.u[7] = f2b(f1.w);
        *(uint4*)(Vs + r * 136 + seg * 8) = o.v;
    }
    __syncthreads();

    short8 xb[4], xv[4];
#pragma unroll
    for (int kc = 0; kc < 4; kc++) {
        xb[kc] = *(const short8*)(Xs + col * 136 + kc * 32 + quad * 8);
        xv[kc] = *(const short8*)(Vs + col * 136 + kc * 32 + quad * 8);
    }
    f32x4 Q[2] = {}, K[2] = {}, V[2] = {};
#pragma unroll
    for (int j = 0; j < 2; j++) {
        int h = 2 * w + j;
#pragma unroll
        for (int kc = 0; kc < 4; kc++) {
            short8 aq = *(const short8*)(WQK + (size_t)(h * 16 + col) * 128 + kc * 32 + quad * 8);
            short8 ak = *(const short8*)(WQK + (size_t)((128 + h * 16) + col) * 128 + kc * 32 + quad * 8);
            short8 av = *(const short8*)(WV + (size_t)(h * 16 + col) * 128 + kc * 32 + quad * 8);
            Q[j] = __builtin_amdgcn_mfma_f32_16x16x32_bf16(aq, xb[kc], Q[j], 0, 0, 0);
            K[j] = __builtin_amdgcn_mfma_f32_16x16x32_bf16(ak, xb[kc], K[j], 0, 0, 0);
            V[j] = __builtin_amdgcn_mfma_f32_16x16x32_bf16(av, xv[kc], V[j], 0, 0, 0);
        }
    }

    const int l = l0 + col;
#pragma unroll
    for (int j = 0; j < 2; j++) {
        int h = 2 * w + j;
        size_t base = ((size_t)(bn * 8 + h) * 1024 + l) * 16 + quad * 4;
        ushort4 oq, ok, ov;
        oq.x = f2b(Q[j][0]); oq.y = f2b(Q[j][1]); oq.z = f2b(Q[j][2]); oq.w = f2b(Q[j][3]);
        ok.x = f2b(K[j][0]); ok.y = f2b(K[j][1]); ok.z = f2b(K[j][2]); ok.w = f2b(K[j][3]);
        ov.x = f2b(V[j][0]); ov.y = f2b(V[j][1]); ov.z = f2b(V[j][2]); ov.w = f2b(V[j][3]);
        *(ushort4*)(Qh + base) = oq;
        *(ushort4*)(Kh + base) = ok;
        *(ushort4*)(Vh + base) = ov;
    }
}

// ---------------------------------------------------------------------------
// MFMA local-window attention (unchanged from R3).
// ---------------------------------------------------------------------------
__global__ __launch_bounds__(256) void k_attn(
    const ushort* __restrict__ Qh, const ushort* __restrict__ Kh,
    const ushort* __restrict__ Vh, ushort* __restrict__ AO)
{
    __shared__ ushort VT[4][16 * 168];
    const int t = threadIdx.x, w = t >> 6, lane = t & 63;
    const int col = lane & 15, quad = lane >> 4;
    const int wid = blockIdx.x * 4 + w;
    const int y = wid & 31, h = (wid >> 5) & 7, n = wid >> 8;
    const size_t base = (size_t)(n * 8 + h) * 1024;

    for (int i = lane; i < 160; i += 64) {
        int kr = i >> 5, kx = i & 31;
        int yyc = min(max(y - 2 + kr, 0), 31);
        const ushort* src = Vh + (base + yyc * 32 + kx) * 16;
        union { uint4 v; ushort u[8]; } ua, ub;
        ua.v = *(const uint4*)(src);
        ub.v = *(const uint4*)(src + 8);
        int pos = (kr << 5) + (((kx & 15) >> 2) << 3) + ((kx >> 4) << 2) + (kx & 3);
        ushort* dst = &VT[w][pos];
#pragma unroll
        for (int d = 0; d < 8; d++) dst[d * 168] = ua.u[d];
#pragma unroll
        for (int d = 0; d < 8; d++) dst[(d + 8) * 168] = ub.u[d];
    }

    short8 z8 = {0, 0, 0, 0, 0, 0, 0, 0};
    short8 qf[2] = { z8, z8 };
#pragma unroll
    for (int j = 0; j < 2; j++)
        if (quad < 2)
            qf[j] = *(const short8*)(Qh + (base + y * 32 + j * 16 + col) * 16 + quad * 8);

    f32x4 S[2][10] = {};
#pragma unroll
    for (int tt = 0; tt < 10; tt++) {
        int kr = tt >> 1, kx = ((tt & 1) << 4) + col;
        int yyc = min(max(y - 2 + kr, 0), 31);
        short8 kf = z8;
        if (quad < 2)
            kf = *(const short8*)(Kh + (base + yyc * 32 + kx) * 16 + quad * 8);
        S[0][tt] = __builtin_amdgcn_mfma_f32_16x16x32_bf16(kf, qf[0], S[0][tt], 0, 0, 0);
        S[1][tt] = __builtin_amdgcn_mfma_f32_16x16x32_bf16(kf, qf[1], S[1][tt], 0, 0, 0);
    }

    float invs[2];
#pragma unroll
    for (int j = 0; j < 2; j++) {
        int qx = j * 16 + col;
        float mx = -1e30f;
#pragma unroll
        for (int tt = 0; tt < 10; tt++) {
            int yy = y - 2 + (tt >> 1);
            bool rok = (yy >= 0) && (yy < 32);
            int kxb = ((tt & 1) << 4) + quad * 4;
#pragma unroll
            for (int r = 0; r < 4; r++) {
                int dd = kxb + r - qx;
                bool ok = rok && ((unsigned)(dd + 2) <= 4u);
                float v = ok ? S[j][tt][r] * 0.25f : -1e30f;
                S[j][tt][r] = v;
                mx = fmaxf(mx, v);
            }
        }
        mx = fmaxf(mx, __shfl_xor(mx, 16, 64));
        mx = fmaxf(mx, __shfl_xor(mx, 32, 64));
        float sum = 0.f;
#pragma unroll
        for (int tt = 0; tt < 10; tt++)
#pragma unroll
            for (int r = 0; r < 4; r++) {
                float p = __expf(S[j][tt][r] - mx);
                S[j][tt][r] = p;
                sum += p;
            }
        sum += __shfl_xor(sum, 16, 64);
        sum += __shfl_xor(sum, 32, 64);
        invs[j] = 1.f / sum;
    }

    f32x4 O[2] = {};
#pragma unroll
    for (int c = 0; c < 5; c++) {
        short8 vt = *(const short8*)(&VT[w][col * 168 + c * 32 + quad * 8]);
#pragma unroll
        for (int j = 0; j < 2; j++) {
            union { ushort u[8]; short8 s; } pb;
#pragma unroll
            for (int i = 0; i < 8; i++)
                pb.u[i] = f2b(S[j][2 * c + (i >> 2)][i & 3] * invs[j]);
            O[j] = __builtin_amdgcn_mfma_f32_16x16x32_bf16(vt, pb.s, O[j], 0, 0, 0);
        }
    }

#pragma unroll
    for (int j = 0; j < 2; j++) {
        int l = y * Lw + j * 16 + col;
        ushort4 o;
        o.x = f2b(O[j][0]); o.y = f2b(O[j][1]); o.z = f2b(O[j][2]); o.w = f2b(O[j][3]);
        *(ushort4*)(AO + ((size_t)l * BN + n) * EE + h * DH + quad * 4) = o;
    }
}

// ---------------------------------------------------------------------------
// out_proj + residual + LN2, 16-token blocks (grid 1600). Wave w: e-tiles
// {2w,2w+1} (8 MFMAs); Y+res -> LDS; LN per token with 16 lanes/token.
// ---------------------------------------------------------------------------
__global__ __launch_bounds__(256) void k_oln(
    const ushort* __restrict__ AO, const ushort* __restrict__ WO,
    const float* __restrict__ g2, const float* __restrict__ b2,
    float* __restrict__ TOK, ushort* __restrict__ XLN2)
{
    __shared__ ushort As[16 * 136];
    __shared__ float  Rs[16 * 132];
    const int m0 = blockIdx.x * 16;
    const int t = threadIdx.x, w = t >> 6, lane = t & 63;
    const int col = lane & 15, quad = lane >> 4;

    {
        int r = t >> 4, seg = t & 15;
        *(uint4*)(As + r * 136 + seg * 8) = *(const uint4*)(AO + (size_t)(m0 + r) * 128 + seg * 8);
        const float4* pt = (const float4*)(TOK + (size_t)(m0 + r) * 128 + seg * 8);
        *(float4*)(Rs + r * 132 + seg * 8)     = pt[0];
        *(float4*)(Rs + r * 132 + seg * 8 + 4) = pt[1];
    }
    __syncthreads();

    short8 xb[4];
#pragma unroll
    for (int kc = 0; kc < 4; kc++)
        xb[kc] = *(const short8*)(As + col * 136 + kc * 32 + quad * 8);

    f32x4 Y[2] = {};
#pragma unroll
    for (int j = 0; j < 2; j++) {
        int et = 2 * w + j;
#pragma unroll
        for (int kc = 0; kc < 4; kc++) {
            short8 a = *(const short8*)(WO + (size_t)(et * 16 + col) * 128 + kc * 32 + quad * 8);
            Y[j] = __builtin_amdgcn_mfma_f32_16x16x32_bf16(a, xb[kc], Y[j], 0, 0, 0);
        }
    }
    // residual add, write back into Rs (unique owner per slot)
#pragma unroll
    for (int j = 0; j < 2; j++)
#pragma unroll
        for (int r = 0; r < 4; r++) {
            int e = (2 * w + j) * 16 + quad * 4 + r;
            float v = Y[j][r] + Rs[col * 132 + e];
            Rs[col * 132 + e] = v;
        }
    __syncthreads();

    // LN: wave w handles tokens 4w..4w+3; 16 lanes per token, 8 e's per lane
    {
        int tsub = lane >> 4, idx = lane & 15, token = 4 * w + tsub;
        int e0 = idx * 8;
        float4 v0 = *(const float4*)(Rs + token * 132 + e0);
        float4 v1 = *(const float4*)(Rs + token * 132 + e0 + 4);
        float s = v0.x + v0.y + v0.z + v0.w + v1.x + v1.y + v1.z + v1.w;
        float q = v0.x * v0.x + v0.y * v0.y + v0.z * v0.z + v0.w * v0.w
                + v1.x * v1.x + v1.y * v1.y + v1.z * v1.z + v1.w * v1.w;
#pragma unroll
        for (int m = 1; m < 16; m <<= 1) {
            s += __shfl_xor(s, m, 64);
            q += __shfl_xor(q, m, 64);
        }
        float mean = s * (1.f / 128.f);
        float var  = q * (1.f / 128.f) - mean * mean;
        float rstd = rsqrtf(var + 1e-5f);
        float4 g0 = *(const float4*)(g2 + e0), g1v = *(const float4*)(g2 + e0 + 4);
        float4 b0 = *(const float4*)(b2 + e0), b1v = *(const float4*)(b2 + e0 + 4);
        size_t rowo = (size_t)(m0 + token) * 128 + e0;
        *(float4*)(TOK + rowo)     = v0;
        *(float4*)(TOK + rowo + 4) = v1;
        union { ushort u[8]; uint4 v; } o;
        o.u[0] = f2b((v0.x - mean) * rstd * g0.x + b0.x);
        o.u[1] = f2b((v0.y - mean) * rstd * g0.y + b0.y);
        o.u[2] = f2b((v0.z - mean) * rstd * g0.z + b0.z);
        o.u[3] = f2b((v0.w - mean) * rstd * g0.w + b0.w);
        o.u[4] = f2b((v1.x - mean) * rstd * g1v.x + b1v.x);
        o.u[5] = f2b((v1.y - mean) * rstd * g1v.y + b1v.y);
        o.u[6] = f2b((v1.z - mean) * rstd * g1v.z + b1v.z);
        o.u[7] = f2b((v1.w - mean) * rstd * g1v.w + b1v.w);
        *(uint4*)(XLN2 + rowo) = o.v;
    }
}

// ---------------------------------------------------------------------------
// Fused FFN+conv, 16-token blocks (grid 1600). Wave w: phase1 ft {4w..4w+3}
// -> relu-pack to Hs (permuted); phase2 et {2w,2w+1} from Hs -> +res (from
// pre-permuted Rsp) -> pack to Ys; phase3 ot=w conv -> coalesced out store.
// ---------------------------------------------------------------------------
__global__ __launch_bounds__(256) void k_ffn(
    const ushort* __restrict__ XLN2, const float* __restrict__ TOK,
    const ushort* __restrict__ W1, const ushort* __restrict__ W2P,
    const ushort* __restrict__ WCP, float* __restrict__ out)
{
    __shared__ ushort Xs[16 * 136];
    __shared__ float  Rsp[16 * 132];
    __shared__ ushort Hs[16 * 264];
    __shared__ ushort Ys[16 * 136];
    const int b = blockIdx.x, bn = b % 25, l0 = (b / 25) * 16;
    const int t = threadIdx.x, w = t >> 6, lane = t & 63;
    const int col = lane & 15, quad = lane >> 4;

    {
        int r = t >> 4, seg = t & 15;
        size_t m = (size_t)(l0 + r) * 25 + bn;
        *(uint4*)(Xs + r * 136 + seg * 8) = *(const uint4*)(XLN2 + m * 128 + seg * 8);
        const float4* pt = (const float4*)(TOK + m * 128 + seg * 8);
        float4 f0 = pt[0], f1 = pt[1];
        float fv[8] = { f0.x, f0.y, f0.z, f0.w, f1.x, f1.y, f1.z, f1.w };
#pragma unroll
        for (int j = 0; j < 8; j++) {
            int e = seg * 8 + j;
            int c = e >> 5, half = (e >> 4) & 1, q = (e >> 2) & 3, r2 = e & 3;
            Rsp[r * 132 + c * 32 + q * 8 + half * 4 + r2] = fv[j];
        }
    }
    __syncthreads();

    short8 xb[4];
#pragma unroll
    for (int kc = 0; kc < 4; kc++)
        xb[kc] = *(const short8*)(Xs + col * 136 + kc * 32 + quad * 8);

    // phase 1: ft = 4w..4w+3
    f32x4 H[4] = {};
#pragma unroll
    for (int j = 0; j < 4; j++) {
        int ft = 4 * w + j;
#pragma unroll
        for (int kc = 0; kc < 4; kc++) {
            short8 a = *(const short8*)(W1 + (size_t)(ft * 16 + col) * 128 + kc * 32 + quad * 8);
            H[j] = __builtin_amdgcn_mfma_f32_16x16x32_bf16(a, xb[kc], H[j], 0, 0, 0);
        }
    }
#pragma unroll
    for (int cc = 0; cc < 2; cc++) {
        union { ushort u[8]; uint4 v; } pb;
#pragma unroll
        for (int i = 0; i < 8; i++)
            pb.u[i] = f2b(fmaxf(H[2 * cc + (i >> 2)][i & 3], 0.f));
        *(uint4*)(Hs + col * 264 + (2 * w + cc) * 32 + quad * 8) = pb.v;
    }
    __syncthreads();

    // phase 2: et = 2w, 2w+1 over K=256 from Hs
    f32x4 Y[2] = {};
#pragma unroll
    for (int kc = 0; kc < 8; kc++) {
        short8 hb = *(const short8*)(Hs + col * 264 + kc * 32 + quad * 8);
#pragma unroll
        for (int j = 0; j < 2; j++) {
            int et = 2 * w + j;
            short8 a = *(const short8*)(W2P + (size_t)(et * 16 + col) * 256 + kc * 32 + quad * 8);
            Y[j] = __builtin_amdgcn_mfma_f32_16x16x32_bf16(a, hb, Y[j], 0, 0, 0);
        }
    }
    // residual (pre-permuted) + pack to Ys
    {
        float4 r0 = *(const float4*)(Rsp + col * 132 + w * 32 + quad * 8);
        float4 r1 = *(const float4*)(Rsp + col * 132 + w * 32 + quad * 8 + 4);
        union { ushort u[8]; uint4 v; } pb;
        pb.u[0] = f2b(Y[0][0] + r0.x); pb.u[1] = f2b(Y[0][1] + r0.y);
        pb.u[2] = f2b(Y[0][2] + r0.z); pb.u[3] = f2b(Y[0][3] + r0.w);
        pb.u[4] = f2b(Y[1][0] + r1.x); pb.u[5] = f2b(Y[1][1] + r1.y);
        pb.u[6] = f2b(Y[1][2] + r1.z); pb.u[7] = f2b(Y[1][3] + r1.w);
        *(uint4*)(Ys + col * 136 + w * 32 + quad * 8) = pb.v;
    }
    __syncthreads();

    // phase 3: conv, ot = w
    f32x4 O = {};
#pragma unroll
    for (int c = 0; c < 4; c++) {
        short8 yb = *(const short8*)(Ys + col * 136 + c * 32 + quad * 8);
        short8 a = *(const short8*)(WCP + (size_t)(w * 16 + col) * 128 + c * 32 + quad * 8);
        O = __builtin_amdgcn_mfma_f32_16x16x32_bf16(a, yb, O, 0, 0, 0);
    }
    const int l = l0 + col;
#pragma unroll
    for (int r2 = 0; r2 < 4; r2++) {
        int o = w * 16 + quad * 4 + r2;
        out[(size_t)(o * 25 + bn) * 1024 + l] = O[r2];
    }
}

// ---------------------------------------------------------------------------
// Launch
// ---------------------------------------------------------------------------
extern "C" void kernel_launch(void* const* d_in, const int* in_sizes, int n_in,
                              void* d_out, int out_size, void* d_ws, size_t ws_size,
                              hipStream_t stream)
{
    const float* buffer   = (const float*)d_in[0];
    const float* spa      = (const float*)d_in[1];
    const float* w_mlp    = (const float*)d_in[2];
    const float* ln1_g    = (const float*)d_in[3];
    const float* ln1_b    = (const float*)d_in[4];
    const float* in_proj  = (const float*)d_in[5];
    const float* out_proj = (const float*)d_in[6];
    const float* ln2_g    = (const float*)d_in[7];
    const float* ln2_b    = (const float*)d_in[8];
    const float* ff_w1    = (const float*)d_in[9];
    const float* ff_w2    = (const float*)d_in[10];
    const float* conv_w   = (const float*)d_in[11];
    float* out = (float*)d_out;

    char* ws = (char*)d_ws;
    float*  TOK  = (float*)(ws);                 // 13,107,200 fp32 residual
    ushort* XLN  = (ushort*)(ws + 13107200);     //  6,553,600 ln1 out bf16
    ushort* Qh   = (ushort*)(ws + 19660800);     //  6,553,600 [n][h][l][d]
    ushort* Kh   = (ushort*)(ws + 26214400);     //  6,553,600
    ushort* Vh   = (ushort*)(ws + 32768000);     //  6,553,600
    ushort* AO   = (ushort*)(ws + 39321600);     //  6,553,600 attn out [l][n][e]
    ushort* XLN2 = (ushort*)(ws + 45875200);     //  6,553,600 ln2 out bf16
    ushort* Tbf  = (ushort*)(ws + 52428800);     //  3,276,800
    ushort* Sbf  = (ushort*)(ws + 55705600);     //  3,276,800
    ushort* Wb   = (ushort*)(ws + 58982400);     //    425,984

    k_prep_w<<<dim3((W_TOTAL + 255) / 256), 256, 0, stream>>>(
        w_mlp, in_proj, out_proj, ff_w1, ff_w2, conv_w, Wb);
    k_prep_in<<<dim3(BN, Lh), 256, 0, stream>>>(buffer, spa, Tbf, Sbf);
    k_token_mfma<<<dim3(BN, Lh), 256, 0, stream>>>(Tbf, Sbf, Wb + OFF_W2,
                                                   ln1_g, ln1_b, TOK, XLN);
    k_qkv<<<dim3(1600), 256, 0, stream>>>(XLN, TOK, Wb + OFF_WQK, Wb + OFF_WV,
                                          Qh, Kh, Vh);
    k_attn<<<dim3(1600), 256, 0, stream>>>(Qh, Kh, Vh, AO);
    k_oln<<<dim3(1600), 256, 0, stream>>>(AO, Wb + OFF_WO, ln2_g, ln2_b, TOK, XLN2);
    k_ffn<<<dim3(1600), 256, 0, stream>>>(XLN2, TOK, Wb + OFF_W1, Wb + OFF_W2F,
                                          Wb + OFF_WC, out);
}

// Round 6
// 191.803 us; speedup vs baseline: 1.1676x; 1.0815x over previous
//
#include <hip/hip_runtime.h>
#include <math.h>

// SpaTrans on MI355X. R6: 5-launch pipeline.
//  k_tok_qkv  = token-embed + LN1 + QKV projections (XLN stays in LDS)
//  k_attn_oln = local attention + out_proj + residual + LN2 (AO stays in LDS)
//  k_ffn      = ff1+relu+ff2+residual+conv (R5 structure, TOKb bf16)
// Residual stream TOKb stored bf16 (error budget: 5x headroom at R5).
#define Lh 32
#define Lw 32
#define LL 1024
#define BN 25
#define EE 128
#define CC 64
#define NHD 8
#define DH 16
#define FFD 256
#define MROWS 25600

typedef __attribute__((ext_vector_type(8))) short short8;
typedef __attribute__((ext_vector_type(4))) float f32x4;

__device__ inline ushort f2b(float x) {
    union { float f; unsigned u; } v; v.f = x;
    unsigned r = (v.u + 0x7fffu + ((v.u >> 16) & 1u)) >> 16;
    return (ushort)r;
}
__device__ inline float b2f(ushort u) {
    union { unsigned u; float f; } v; v.u = ((unsigned)u) << 16;
    return v.f;
}
__device__ inline void unpack8(uint4 p, float* dst) {
    unsigned vals[4] = { p.x, p.y, p.z, p.w };
#pragma unroll
    for (int i = 0; i < 4; i++) {
        union { unsigned u; float f; } lo, hi;
        lo.u = (vals[i] & 0xffffu) << 16;
        hi.u = vals[i] & 0xffff0000u;
        dst[2 * i] = lo.f; dst[2 * i + 1] = hi.f;
    }
}

// ---------------------------------------------------------------------------
// Weight prep. W2 K-reordered (k'=tap*64+ch). WO, W2F, WC k-PERMUTED so the
// previous stage's C-frags pack directly as the B-operand:
// kpos=c*32+q*8+i  <->  orig k=(2c+(i>>2))*16+q*4+(i&3)
// ---------------------------------------------------------------------------
#define OFF_W2  0
#define OFF_WQK 73728
#define OFF_WV  106496
#define OFF_WO  122880
#define OFF_W1  139264
#define OFF_W2F 172032
#define OFF_WC  204800
#define W_TOTAL 212992

__global__ __launch_bounds__(256) void k_prep_w(
    const float* __restrict__ w_mlp, const float* __restrict__ in_proj,
    const float* __restrict__ out_proj, const float* __restrict__ ff_w1,
    const float* __restrict__ ff_w2, const float* __restrict__ conv_w,
    ushort* __restrict__ Wb)
{
    int i = blockIdx.x * 256 + threadIdx.x;
    if (i >= W_TOTAL) return;
    if (i < 73728) {
        int e = i / 576, k = i - e * 576;
        int tap = k >> 6, ch = k & 63;
        Wb[OFF_W2 + i] = f2b(w_mlp[e * 576 + ch * 9 + tap]);
        return;
    }
    i -= 73728;
    if (i < 32768) { Wb[OFF_WQK + i] = f2b(in_proj[i]); return; }
    i -= 32768;
    if (i < 16384) { Wb[OFF_WV + i] = f2b(in_proj[32768 + i]); return; }
    i -= 16384;
    if (i < 16384) {   // WO, k-permuted (K=128)
        int e = i >> 7, kpos = i & 127;
        int c = kpos >> 5, q = (kpos >> 3) & 3, ii = kpos & 7;
        int orig = (2 * c + (ii >> 2)) * 16 + q * 4 + (ii & 3);
        Wb[OFF_WO + i] = f2b(out_proj[e * 128 + orig]);
        return;
    }
    i -= 16384;
    if (i < 32768) { Wb[OFF_W1 + i] = f2b(ff_w1[i]); return; }
    i -= 32768;
    if (i < 32768) {   // W2F, k-permuted (K=256)
        int e = i >> 8, kpos = i & 255;
        int c = kpos >> 5, q = (kpos >> 3) & 3, ii = kpos & 7;
        int orig = (2 * c + (ii >> 2)) * 16 + q * 4 + (ii & 3);
        Wb[OFF_W2F + i] = f2b(ff_w2[e * 256 + orig]);
        return;
    }
    i -= 32768;
    {                  // WC, k-permuted (K=128)
        int o = i >> 7, kpos = i & 127;
        int c = kpos >> 5, q = (kpos >> 3) & 3, ii = kpos & 7;
        int orig = (2 * c + (ii >> 2)) * 16 + q * 4 + (ii & 3);
        Wb[OFF_WC + i] = f2b(conv_w[o * 128 + orig]);
    }
}

// ---------------------------------------------------------------------------
// Input prep (unchanged).
// ---------------------------------------------------------------------------
__global__ __launch_bounds__(256) void k_prep_in(
    const float* __restrict__ buf, const float* __restrict__ spa,
    ushort* __restrict__ T, ushort* __restrict__ S)
{
    const int n = blockIdx.x, y = blockIdx.y;
    __shared__ float t0[64][33];
    __shared__ float t1[64][33];
    const int t = threadIdx.x;
    {
        int ch = t >> 2, x8 = (t & 3) * 8;
        const float* p = buf + ((size_t)(ch * BN + n) * LL + y * Lw + x8);
        const float* q = spa + ((size_t)(ch * BN + n) * LL + y * Lw + x8);
        float4 a0 = ((const float4*)p)[0], a1 = ((const float4*)p)[1];
        float4 b0 = ((const float4*)q)[0], b1 = ((const float4*)q)[1];
        float* d0 = &t0[ch][x8];
        float* d1 = &t1[ch][x8];
        d0[0] = a0.x; d0[1] = a0.y; d0[2] = a0.z; d0[3] = a0.w;
        d0[4] = a1.x; d0[5] = a1.y; d0[6] = a1.z; d0[7] = a1.w;
        d1[0] = a0.x + b0.x; d1[1] = a0.y + b0.y; d1[2] = a0.z + b0.z; d1[3] = a0.w + b0.w;
        d1[4] = a1.x + b1.x; d1[5] = a1.y + b1.y; d1[6] = a1.z + b1.z; d1[7] = a1.w + b1.w;
    }
    __syncthreads();
    {
        int x = t >> 3, c8 = (t & 7) * 8;
        union { ushort u[8]; uint4 v; } o0, o1;
#pragma unroll
        for (int j = 0; j < 8; j++) { o0.u[j] = f2b(t0[c8 + j][x]); o1.u[j] = f2b(t1[c8 + j][x]); }
        size_t base = (((size_t)n * Lh + y) * Lw + x) * 64 + c8;
        *(uint4*)(T + base) = o0.v;
        *(uint4*)(S + base) = o1.v;
    }
}

// ---------------------------------------------------------------------------
// Token embed + LN1 + QKV, fused. Block (n,y) = 32 tokens.
// Phase A: im2col MFMA -> accT (tok), accS (tok+pe); LN1 -> Xs (LDS bf16);
//          bf16(tok) -> Vs (LDS). Phase B: QKV MFMAs (heads split on waves),
//          coalesced TOKb write from Vs.
// ---------------------------------------------------------------------------
__global__ __launch_bounds__(256) void k_tok_qkv(
    const ushort* __restrict__ T, const ushort* __restrict__ S,
    const ushort* __restrict__ W2, const ushort* __restrict__ WQK,
    const ushort* __restrict__ WV, const float* __restrict__ g1,
    const float* __restrict__ b1, ushort* __restrict__ TOKb,
    ushort* __restrict__ Qh, ushort* __restrict__ Kh, ushort* __restrict__ Vh)
{
    const int n = blockIdx.x, y = blockIdx.y;
    __shared__ ushort At[3 * 34 * 72];
    __shared__ ushort As_[3 * 34 * 72];
    __shared__ ushort Xs[32 * 136];
    __shared__ ushort Vs[32 * 136];
    __shared__ float2 red[32][4];
    const int t = threadIdx.x;
    const uint4 z = make_uint4(0, 0, 0, 0);

    {
        int x = t >> 3, c8 = (t & 7) * 8;
#pragma unroll
        for (int dy = 0; dy < 3; dy++) {
            int yy = y + dy - 1;
            uint4 va = z, vs = z;
            if (yy >= 0 && yy < Lh) {
                size_t gi = (((size_t)n * Lh + yy) * Lw + x) * 64 + c8;
                va = *(const uint4*)(T + gi);
                vs = *(const uint4*)(S + gi);
            }
            *(uint4*)(At + (dy * 34 + x + 1) * 72 + c8) = va;
            *(uint4*)(As_ + (dy * 34 + x + 1) * 72 + c8) = vs;
        }
        if (t < 48) {
            int dy = t / 16, rem = t % 16;
            int colp = (rem >> 3) * 33, c8p = (rem & 7) * 8;
            *(uint4*)(At + (dy * 34 + colp) * 72 + c8p) = z;
            *(uint4*)(As_ + (dy * 34 + colp) * 72 + c8p) = z;
        }
    }
    __syncthreads();

    const int w = t >> 6, lane = t & 63;
    const int col = lane & 15, quad = lane >> 4;
    f32x4 accT[2][2] = {}, accS[2][2] = {};

    for (int tap = 0; tap < 9; tap++) {
        int dy = tap / 3, dx = tap % 3;
#pragma unroll
        for (int cc = 0; cc < 2; cc++) {
            int kg = tap * 64 + cc * 32 + quad * 8;
            short8 b0 = *(const short8*)(W2 + (size_t)(w * 32 + col) * 576 + kg);
            short8 bq = *(const short8*)(W2 + (size_t)(w * 32 + 16 + col) * 576 + kg);
            int abase = (dy * 34 + col + dx) * 72 + cc * 32 + quad * 8;
            short8 aT0 = *(const short8*)(At + abase);
            short8 aT1 = *(const short8*)(At + abase + 16 * 72);
            short8 aS0 = *(const short8*)(As_ + abase);
            short8 aS1 = *(const short8*)(As_ + abase + 16 * 72);
            accT[0][0] = __builtin_amdgcn_mfma_f32_16x16x32_bf16(aT0, b0, accT[0][0], 0, 0, 0);
            accT[0][1] = __builtin_amdgcn_mfma_f32_16x16x32_bf16(aT0, bq, accT[0][1], 0, 0, 0);
            accT[1][0] = __builtin_amdgcn_mfma_f32_16x16x32_bf16(aT1, b0, accT[1][0], 0, 0, 0);
            accT[1][1] = __builtin_amdgcn_mfma_f32_16x16x32_bf16(aT1, bq, accT[1][1], 0, 0, 0);
            accS[0][0] = __builtin_amdgcn_mfma_f32_16x16x32_bf16(aS0, b0, accS[0][0], 0, 0, 0);
            accS[0][1] = __builtin_amdgcn_mfma_f32_16x16x32_bf16(aS0, bq, accS[0][1], 0, 0, 0);
            accS[1][0] = __builtin_amdgcn_mfma_f32_16x16x32_bf16(aS1, b0, accS[1][0], 0, 0, 0);
            accS[1][1] = __builtin_amdgcn_mfma_f32_16x16x32_bf16(aS1, bq, accS[1][1], 0, 0, 0);
        }
    }

    // LN1 partial sums
#pragma unroll
    for (int mi = 0; mi < 2; mi++)
#pragma unroll
        for (int r = 0; r < 4; r++) {
            float a0 = accS[mi][0][r], a1 = accS[mi][1][r];
            float ss = a0 + a1, qq = a0 * a0 + a1 * a1;
#pragma unroll
            for (int m = 1; m < 16; m <<= 1) {
                ss += __shfl_xor(ss, m, 64);
                qq += __shfl_xor(qq, m, 64);
            }
            if (col == 0) red[mi * 16 + quad * 4 + r][w] = make_float2(ss, qq);
        }
    __syncthreads();

    const float ga = g1[w * 32 + col],      ba = b1[w * 32 + col];
    const float gb = g1[w * 32 + 16 + col], bb = b1[w * 32 + 16 + col];
#pragma unroll
    for (int mi = 0; mi < 2; mi++)
#pragma unroll
        for (int r = 0; r < 4; r++) {
            int x = mi * 16 + quad * 4 + r;
            float2 p0 = red[x][0], p1 = red[x][1], p2 = red[x][2], p3 = red[x][3];
            float mean = (p0.x + p1.x + p2.x + p3.x) * (1.f / 128.f);
            float var  = (p0.y + p1.y + p2.y + p3.y) * (1.f / 128.f) - mean * mean;
            float rstd = rsqrtf(var + 1e-5f);
            int e0 = w * 32 + col, e1 = w * 32 + 16 + col;
            Xs[x * 136 + e0] = f2b((accS[mi][0][r] - mean) * rstd * ga + ba);
            Xs[x * 136 + e1] = f2b((accS[mi][1][r] - mean) * rstd * gb + bb);
            Vs[x * 136 + e0] = f2b(accT[mi][0][r]);
            Vs[x * 136 + e1] = f2b(accT[mi][1][r]);
        }
    __syncthreads();

    // phase B: QKV. Wave w -> heads 2w, 2w+1; token tiles j=0,1.
    short8 xb[2][4], xv[2][4];
#pragma unroll
    for (int j = 0; j < 2; j++)
#pragma unroll
        for (int kc = 0; kc < 4; kc++) {
            xb[j][kc] = *(const short8*)(Xs + (j * 16 + col) * 136 + kc * 32 + quad * 8);
            xv[j][kc] = *(const short8*)(Vs + (j * 16 + col) * 136 + kc * 32 + quad * 8);
        }
    f32x4 Q[2][2] = {}, K[2][2] = {}, V[2][2] = {};
#pragma unroll
    for (int hj = 0; hj < 2; hj++) {
        int h = 2 * w + hj;
#pragma unroll
        for (int kc = 0; kc < 4; kc++) {
            short8 aq = *(const short8*)(WQK + (size_t)(h * 16 + col) * 128 + kc * 32 + quad * 8);
            short8 ak = *(const short8*)(WQK + (size_t)(128 + h * 16 + col) * 128 + kc * 32 + quad * 8);
            short8 av = *(const short8*)(WV + (size_t)(h * 16 + col) * 128 + kc * 32 + quad * 8);
#pragma unroll
            for (int j = 0; j < 2; j++) {
                Q[hj][j] = __builtin_amdgcn_mfma_f32_16x16x32_bf16(aq, xb[j][kc], Q[hj][j], 0, 0, 0);
                K[hj][j] = __builtin_amdgcn_mfma_f32_16x16x32_bf16(ak, xb[j][kc], K[hj][j], 0, 0, 0);
                V[hj][j] = __builtin_amdgcn_mfma_f32_16x16x32_bf16(av, xv[j][kc], V[hj][j], 0, 0, 0);
            }
        }
    }
#pragma unroll
    for (int hj = 0; hj < 2; hj++)
#pragma unroll
        for (int j = 0; j < 2; j++) {
            int h = 2 * w + hj;
            int l = y * 32 + j * 16 + col;
            size_t base = ((size_t)(n * 8 + h) * 1024 + l) * 16 + quad * 4;
            ushort4 oq, ok, ov;
            oq.x = f2b(Q[hj][j][0]); oq.y = f2b(Q[hj][j][1]); oq.z = f2b(Q[hj][j][2]); oq.w = f2b(Q[hj][j][3]);
            ok.x = f2b(K[hj][j][0]); ok.y = f2b(K[hj][j][1]); ok.z = f2b(K[hj][j][2]); ok.w = f2b(K[hj][j][3]);
            ov.x = f2b(V[hj][j][0]); ov.y = f2b(V[hj][j][1]); ov.z = f2b(V[hj][j][2]); ov.w = f2b(V[hj][j][3]);
            *(ushort4*)(Qh + base) = oq;
            *(ushort4*)(Kh + base) = ok;
            *(ushort4*)(Vh + base) = ov;
        }
    // coalesced TOKb write from Vs
#pragma unroll
    for (int k = 0; k < 2; k++) {
        int idx = t + k * 256;
        int r = idx >> 4, seg = idx & 15;
        *(uint4*)(TOKb + ((size_t)((y * 32 + r) * 25 + n)) * 128 + seg * 8) =
            *(const uint4*)(Vs + r * 136 + seg * 8);
    }
}

// ---------------------------------------------------------------------------
// Attention + out_proj + residual + LN2, fused. Block (y,n); wave w = heads
// {2w, 2w+1}. PV C-frags pack as out_proj B-operand (WO pre-permuted).
// ---------------------------------------------------------------------------
__global__ __launch_bounds__(256) void k_attn_oln(
    const ushort* __restrict__ Qh, const ushort* __restrict__ Kh,
    const ushort* __restrict__ Vh, const ushort* __restrict__ WOP,
    const float* __restrict__ g2, const float* __restrict__ b2,
    ushort* __restrict__ TOKb, ushort* __restrict__ XLN2)
{
    __shared__ ushort VT[4][16 * 168];
    __shared__ ushort OX[32 * 136];
    __shared__ ushort Rs[32 * 136];
    __shared__ float2 red[32][4];
    const int y = blockIdx.x, n = blockIdx.y;
    const int t = threadIdx.x, w = t >> 6, lane = t & 63;
    const int col = lane & 15, quad = lane >> 4;

    {   // stage residual rows (bf16)
        int r = t >> 3, seg = t & 7;
        const uint4* src = (const uint4*)(TOKb + ((size_t)((y * 32 + r) * 25 + n)) * 128 + seg * 16);
        *(uint4*)(Rs + r * 136 + seg * 16)     = src[0];
        *(uint4*)(Rs + r * 136 + seg * 16 + 8) = src[1];
    }

    short8 z8 = {0, 0, 0, 0, 0, 0, 0, 0};
    f32x4 O2[2][2] = {};
#pragma unroll
    for (int hj = 0; hj < 2; hj++) {
        const int h = 2 * w + hj;
        const size_t base = (size_t)(n * 8 + h) * 1024;
        // stage V^T permuted (wave-private)
        for (int i = lane; i < 160; i += 64) {
            int kr = i >> 5, kx = i & 31;
            int yyc = min(max(y - 2 + kr, 0), 31);
            const ushort* src = Vh + (base + yyc * 32 + kx) * 16;
            union { uint4 v; ushort u[8]; } ua, ub;
            ua.v = *(const uint4*)(src);
            ub.v = *(const uint4*)(src + 8);
            int pos = (kr << 5) + (((kx & 15) >> 2) << 3) + ((kx >> 4) << 2) + (kx & 3);
            ushort* dst = &VT[w][pos];
#pragma unroll
            for (int d = 0; d < 8; d++) dst[d * 168] = ua.u[d];
#pragma unroll
            for (int d = 0; d < 8; d++) dst[(d + 8) * 168] = ub.u[d];
        }

        short8 qf[2] = { z8, z8 };
#pragma unroll
        for (int j = 0; j < 2; j++)
            if (quad < 2)
                qf[j] = *(const short8*)(Qh + (base + y * 32 + j * 16 + col) * 16 + quad * 8);

        f32x4 Sc[2][10] = {};
#pragma unroll
        for (int tt = 0; tt < 10; tt++) {
            int kr = tt >> 1, kx = ((tt & 1) << 4) + col;
            int yyc = min(max(y - 2 + kr, 0), 31);
            short8 kf = z8;
            if (quad < 2)
                kf = *(const short8*)(Kh + (base + yyc * 32 + kx) * 16 + quad * 8);
            Sc[0][tt] = __builtin_amdgcn_mfma_f32_16x16x32_bf16(kf, qf[0], Sc[0][tt], 0, 0, 0);
            Sc[1][tt] = __builtin_amdgcn_mfma_f32_16x16x32_bf16(kf, qf[1], Sc[1][tt], 0, 0, 0);
        }

        float invs[2];
#pragma unroll
        for (int j = 0; j < 2; j++) {
            int qx = j * 16 + col;
            float mx = -1e30f;
#pragma unroll
            for (int tt = 0; tt < 10; tt++) {
                int yy = y - 2 + (tt >> 1);
                bool rok = (yy >= 0) && (yy < 32);
                int kxb = ((tt & 1) << 4) + quad * 4;
#pragma unroll
                for (int r = 0; r < 4; r++) {
                    int dd = kxb + r - qx;
                    bool ok = rok && ((unsigned)(dd + 2) <= 4u);
                    float v = ok ? Sc[j][tt][r] * 0.25f : -1e30f;
                    Sc[j][tt][r] = v;
                    mx = fmaxf(mx, v);
                }
            }
            mx = fmaxf(mx, __shfl_xor(mx, 16, 64));
            mx = fmaxf(mx, __shfl_xor(mx, 32, 64));
            float sum = 0.f;
#pragma unroll
            for (int tt = 0; tt < 10; tt++)
#pragma unroll
                for (int r = 0; r < 4; r++) {
                    float p = __expf(Sc[j][tt][r] - mx);
                    Sc[j][tt][r] = p;
                    sum += p;
                }
            sum += __shfl_xor(sum, 16, 64);
            sum += __shfl_xor(sum, 32, 64);
            invs[j] = 1.f / sum;
        }

#pragma unroll
        for (int c = 0; c < 5; c++) {
            short8 vt = *(const short8*)(&VT[w][col * 168 + c * 32 + quad * 8]);
#pragma unroll
            for (int j = 0; j < 2; j++) {
                union { ushort u[8]; short8 s; } pb;
#pragma unroll
                for (int i = 0; i < 8; i++)
                    pb.u[i] = f2b(Sc[j][2 * c + (i >> 2)][i & 3] * invs[j]);
                O2[hj][j] = __builtin_amdgcn_mfma_f32_16x16x32_bf16(vt, pb.s, O2[hj][j], 0, 0, 0);
            }
        }
    }

    // pack O (heads 2w,2w+1) -> OX as B-operand k-slice w
#pragma unroll
    for (int j = 0; j < 2; j++) {
        union { ushort u[8]; uint4 v; } pb;
#pragma unroll
        for (int i = 0; i < 8; i++)
            pb.u[i] = f2b(O2[i >> 2][j][i & 3]);
        *(uint4*)(OX + (j * 16 + col) * 136 + w * 32 + quad * 8) = pb.v;
    }
    __syncthreads();

    // out_proj: wave w -> e-tiles {2w, 2w+1}
    f32x4 Y[2][2] = {};
#pragma unroll
    for (int kc = 0; kc < 4; kc++) {
        short8 hb0 = *(const short8*)(OX + col * 136 + kc * 32 + quad * 8);
        short8 hb1 = *(const short8*)(OX + (16 + col) * 136 + kc * 32 + quad * 8);
#pragma unroll
        for (int jj = 0; jj < 2; jj++) {
            int et = 2 * w + jj;
            short8 a = *(const short8*)(WOP + (size_t)(et * 16 + col) * 128 + kc * 32 + quad * 8);
            Y[jj][0] = __builtin_amdgcn_mfma_f32_16x16x32_bf16(a, hb0, Y[jj][0], 0, 0, 0);
            Y[jj][1] = __builtin_amdgcn_mfma_f32_16x16x32_bf16(a, hb1, Y[jj][1], 0, 0, 0);
        }
    }
    // residual + LN2 stats
    float sum[2] = {0.f, 0.f}, sq[2] = {0.f, 0.f};
#pragma unroll
    for (int j = 0; j < 2; j++)
#pragma unroll
        for (int jj = 0; jj < 2; jj++)
#pragma unroll
            for (int r = 0; r < 4; r++) {
                int e = (2 * w + jj) * 16 + quad * 4 + r;
                float v = Y[jj][j][r] + b2f(Rs[(j * 16 + col) * 136 + e]);
                Y[jj][j][r] = v;
                sum[j] += v; sq[j] += v * v;
            }
#pragma unroll
    for (int j = 0; j < 2; j++) {
        sum[j] += __shfl_xor(sum[j], 16, 64); sum[j] += __shfl_xor(sum[j], 32, 64);
        sq[j]  += __shfl_xor(sq[j], 16, 64);  sq[j]  += __shfl_xor(sq[j], 32, 64);
        if (quad == 0) red[j * 16 + col][w] = make_float2(sum[j], sq[j]);
    }
    __syncthreads();

    float mean[2], rstd[2];
#pragma unroll
    for (int j = 0; j < 2; j++) {
        float2 p0 = red[j * 16 + col][0], p1 = red[j * 16 + col][1];
        float2 p2 = red[j * 16 + col][2], p3 = red[j * 16 + col][3];
        mean[j] = (p0.x + p1.x + p2.x + p3.x) * (1.f / 128.f);
        float var = (p0.y + p1.y + p2.y + p3.y) * (1.f / 128.f) - mean[j] * mean[j];
        rstd[j] = rsqrtf(var + 1e-5f);
    }
#pragma unroll
    for (int jj = 0; jj < 2; jj++)
#pragma unroll
        for (int r = 0; r < 4; r++) {
            int e = (2 * w + jj) * 16 + quad * 4 + r;
            float ge = g2[e], be = b2[e];
#pragma unroll
            for (int j = 0; j < 2; j++) {
                float v = Y[jj][j][r];
                Rs[(j * 16 + col) * 136 + e] = f2b(v);
                OX[(j * 16 + col) * 136 + e] = f2b((v - mean[j]) * rstd[j] * ge + be);
            }
        }
    __syncthreads();

    {   // coalesced writes
        int r = t >> 3, seg = t & 7;
        size_t go = ((size_t)((y * 32 + r) * 25 + n)) * 128 + seg * 16;
        *(uint4*)(TOKb + go)     = *(const uint4*)(Rs + r * 136 + seg * 16);
        *(uint4*)(TOKb + go + 8) = *(const uint4*)(Rs + r * 136 + seg * 16 + 8);
        *(uint4*)(XLN2 + go)     = *(const uint4*)(OX + r * 136 + seg * 16);
        *(uint4*)(XLN2 + go + 8) = *(const uint4*)(OX + r * 136 + seg * 16 + 8);
    }
}

// ---------------------------------------------------------------------------
// Fused FFN+conv (R5 structure; residual from bf16 TOKb).
// ---------------------------------------------------------------------------
__global__ __launch_bounds__(256) void k_ffn(
    const ushort* __restrict__ XLN2, const ushort* __restrict__ TOKb,
    const ushort* __restrict__ W1, const ushort* __restrict__ W2P,
    const ushort* __restrict__ WCP, float* __restrict__ out)
{
    __shared__ ushort Xs[16 * 136];
    __shared__ float  Rsp[16 * 132];
    __shared__ ushort Hs[16 * 264];
    __shared__ ushort Ys[16 * 136];
    const int b = blockIdx.x, bn = b % 25, l0 = (b / 25) * 16;
    const int t = threadIdx.x, w = t >> 6, lane = t & 63;
    const int col = lane & 15, quad = lane >> 4;

    {
        int r = t >> 4, seg = t & 15;
        size_t m = (size_t)(l0 + r) * 25 + bn;
        *(uint4*)(Xs + r * 136 + seg * 8) = *(const uint4*)(XLN2 + m * 128 + seg * 8);
        uint4 tb = *(const uint4*)(TOKb + m * 128 + seg * 8);
        float fv[8];
        unpack8(tb, fv);
#pragma unroll
        for (int j = 0; j < 8; j++) {
            int e = seg * 8 + j;
            int c = e >> 5, half = (e >> 4) & 1, q = (e >> 2) & 3, r2 = e & 3;
            Rsp[r * 132 + c * 32 + q * 8 + half * 4 + r2] = fv[j];
        }
    }
    __syncthreads();

    short8 xb[4];
#pragma unroll
    for (int kc = 0; kc < 4; kc++)
        xb[kc] = *(const short8*)(Xs + col * 136 + kc * 32 + quad * 8);

    f32x4 H[4] = {};
#pragma unroll
    for (int j = 0; j < 4; j++) {
        int ft = 4 * w + j;
#pragma unroll
        for (int kc = 0; kc < 4; kc++) {
            short8 a = *(const short8*)(W1 + (size_t)(ft * 16 + col) * 128 + kc * 32 + quad * 8);
            H[j] = __builtin_amdgcn_mfma_f32_16x16x32_bf16(a, xb[kc], H[j], 0, 0, 0);
        }
    }
#pragma unroll
    for (int cc = 0; cc < 2; cc++) {
        union { ushort u[8]; uint4 v; } pb;
#pragma unroll
        for (int i = 0; i < 8; i++)
            pb.u[i] = f2b(fmaxf(H[2 * cc + (i >> 2)][i & 3], 0.f));
        *(uint4*)(Hs + col * 264 + (2 * w + cc) * 32 + quad * 8) = pb.v;
    }
    __syncthreads();

    f32x4 Y[2] = {};
#pragma unroll
    for (int kc = 0; kc < 8; kc++) {
        short8 hb = *(const short8*)(Hs + col * 264 + kc * 32 + quad * 8);
#pragma unroll
        for (int j = 0; j < 2; j++) {
            int et = 2 * w + j;
            short8 a = *(const short8*)(W2P + (size_t)(et * 16 + col) * 256 + kc * 32 + quad * 8);
            Y[j] = __builtin_amdgcn_mfma_f32_16x16x32_bf16(a, hb, Y[j], 0, 0, 0);
        }
    }
    {
        float4 r0 = *(const float4*)(Rsp + col * 132 + w * 32 + quad * 8);
        float4 r1 = *(const float4*)(Rsp + col * 132 + w * 32 + quad * 8 + 4);
        union { ushort u[8]; uint4 v; } pb;
        pb.u[0] = f2b(Y[0][0] + r0.x); pb.u[1] = f2b(Y[0][1] + r0.y);
        pb.u[2] = f2b(Y[0][2] + r0.z); pb.u[3] = f2b(Y[0][3] + r0.w);
        pb.u[4] = f2b(Y[1][0] + r1.x); pb.u[5] = f2b(Y[1][1] + r1.y);
        pb.u[6] = f2b(Y[1][2] + r1.z); pb.u[7] = f2b(Y[1][3] + r1.w);
        *(uint4*)(Ys + col * 136 + w * 32 + quad * 8) = pb.v;
    }
    __syncthreads();

    f32x4 O = {};
#pragma unroll
    for (int c = 0; c < 4; c++) {
        short8 yb = *(const short8*)(Ys + col * 136 + c * 32 + quad * 8);
        short8 a = *(const short8*)(WCP + (size_t)(w * 16 + col) * 128 + c * 32 + quad * 8);
        O = __builtin_amdgcn_mfma_f32_16x16x32_bf16(a, yb, O, 0, 0, 0);
    }
    const int l = l0 + col;
#pragma unroll
    for (int r2 = 0; r2 < 4; r2++) {
        int o = w * 16 + quad * 4 + r2;
        out[(size_t)(o * 25 + bn) * 1024 + l] = O[r2];
    }
}

// ---------------------------------------------------------------------------
// Launch
// ---------------------------------------------------------------------------
extern "C" void kernel_launch(void* const* d_in, const int* in_sizes, int n_in,
                              void* d_out, int out_size, void* d_ws, size_t ws_size,
                              hipStream_t stream)
{
    const float* buffer   = (const float*)d_in[0];
    const float* spa      = (const float*)d_in[1];
    const float* w_mlp    = (const float*)d_in[2];
    const float* ln1_g    = (const float*)d_in[3];
    const float* ln1_b    = (const float*)d_in[4];
    const float* in_proj  = (const float*)d_in[5];
    const float* out_proj = (const float*)d_in[6];
    const float* ln2_g    = (const float*)d_in[7];
    const float* ln2_b    = (const float*)d_in[8];
    const float* ff_w1    = (const float*)d_in[9];
    const float* ff_w2    = (const float*)d_in[10];
    const float* conv_w   = (const float*)d_in[11];
    float* out = (float*)d_out;

    char* ws = (char*)d_ws;
    ushort* TOKb = (ushort*)(ws);                //  6,553,600 residual bf16
    ushort* XLN2 = (ushort*)(ws + 6553600);      //  6,553,600
    ushort* Qh   = (ushort*)(ws + 13107200);     //  6,553,600 [n][h][l][d]
    ushort* Kh   = (ushort*)(ws + 19660800);     //  6,553,600
    ushort* Vh   = (ushort*)(ws + 26214400);     //  6,553,600
    ushort* Tbf  = (ushort*)(ws + 32768000);     //  3,276,800
    ushort* Sbf  = (ushort*)(ws + 36044800);     //  3,276,800
    ushort* Wb   = (ushort*)(ws + 39321600);     //    425,984

    k_prep_w<<<dim3((W_TOTAL + 255) / 256), 256, 0, stream>>>(
        w_mlp, in_proj, out_proj, ff_w1, ff_w2, conv_w, Wb);
    k_prep_in<<<dim3(BN, Lh), 256, 0, stream>>>(buffer, spa, Tbf, Sbf);
    k_tok_qkv<<<dim3(BN, Lh), 256, 0, stream>>>(Tbf, Sbf, Wb + OFF_W2,
                                                Wb + OFF_WQK, Wb + OFF_WV,
                                                ln1_g, ln1_b, TOKb, Qh, Kh, Vh);
    k_attn_oln<<<dim3(Lh, BN), 256, 0, stream>>>(Qh, Kh, Vh, Wb + OFF_WO,
                                                 ln2_g, ln2_b, TOKb, XLN2);
    k_ffn<<<dim3(1600), 256, 0, stream>>>(XLN2, TOKb, Wb + OFF_W1, Wb + OFF_W2F,
                                          Wb + OFF_WC, out);
}

// Round 7
// 183.344 us; speedup vs baseline: 1.2214x; 1.0461x over previous
//
#include <hip/hip_runtime.h>
#include <math.h>

// SpaTrans on MI355X. R7: attention restructured —
//  * V^T (permuted, PV-A-operand layout) is produced by k_tok_qkv (VTg),
//    so k_attn_oln does zero LDS staging for V (was 557K conflict cycles).
//  * attention grid 1600 = (y, n, half): 2x parallelism, half the chain.
//  * XCD-aware block swizzle on tok_qkv and attn_oln for K/V L2 locality.
#define Lh 32
#define Lw 32
#define LL 1024
#define BN 25
#define EE 128
#define CC 64
#define NHD 8
#define DH 16
#define FFD 256
#define MROWS 25600

typedef __attribute__((ext_vector_type(8))) short short8;
typedef __attribute__((ext_vector_type(4))) float f32x4;

__device__ inline ushort f2b(float x) {
    union { float f; unsigned u; } v; v.f = x;
    unsigned r = (v.u + 0x7fffu + ((v.u >> 16) & 1u)) >> 16;
    return (ushort)r;
}
__device__ inline float b2f(ushort u) {
    union { unsigned u; float f; } v; v.u = ((unsigned)u) << 16;
    return v.f;
}
__device__ inline void unpack8(uint4 p, float* dst) {
    unsigned vals[4] = { p.x, p.y, p.z, p.w };
#pragma unroll
    for (int i = 0; i < 4; i++) {
        union { unsigned u; float f; } lo, hi;
        lo.u = (vals[i] & 0xffffu) << 16;
        hi.u = vals[i] & 0xffff0000u;
        dst[2 * i] = lo.f; dst[2 * i + 1] = hi.f;
    }
}

// ---------------------------------------------------------------------------
// Weight prep. W2 K-reordered (k'=tap*64+ch). WO, W2F, WC k-PERMUTED so the
// previous stage's C-frags pack directly as the B-operand:
// kpos=c*32+q*8+i  <->  orig k=(2c+(i>>2))*16+q*4+(i&3)
// ---------------------------------------------------------------------------
#define OFF_W2  0
#define OFF_WQK 73728
#define OFF_WV  106496
#define OFF_WO  122880
#define OFF_W1  139264
#define OFF_W2F 172032
#define OFF_WC  204800
#define W_TOTAL 212992

__global__ __launch_bounds__(256) void k_prep_w(
    const float* __restrict__ w_mlp, const float* __restrict__ in_proj,
    const float* __restrict__ out_proj, const float* __restrict__ ff_w1,
    const float* __restrict__ ff_w2, const float* __restrict__ conv_w,
    ushort* __restrict__ Wb)
{
    int i = blockIdx.x * 256 + threadIdx.x;
    if (i >= W_TOTAL) return;
    if (i < 73728) {
        int e = i / 576, k = i - e * 576;
        int tap = k >> 6, ch = k & 63;
        Wb[OFF_W2 + i] = f2b(w_mlp[e * 576 + ch * 9 + tap]);
        return;
    }
    i -= 73728;
    if (i < 32768) { Wb[OFF_WQK + i] = f2b(in_proj[i]); return; }
    i -= 32768;
    if (i < 16384) { Wb[OFF_WV + i] = f2b(in_proj[32768 + i]); return; }
    i -= 16384;
    if (i < 16384) {   // WO, k-permuted (K=128)
        int e = i >> 7, kpos = i & 127;
        int c = kpos >> 5, q = (kpos >> 3) & 3, ii = kpos & 7;
        int orig = (2 * c + (ii >> 2)) * 16 + q * 4 + (ii & 3);
        Wb[OFF_WO + i] = f2b(out_proj[e * 128 + orig]);
        return;
    }
    i -= 16384;
    if (i < 32768) { Wb[OFF_W1 + i] = f2b(ff_w1[i]); return; }
    i -= 32768;
    if (i < 32768) {   // W2F, k-permuted (K=256)
        int e = i >> 8, kpos = i & 255;
        int c = kpos >> 5, q = (kpos >> 3) & 3, ii = kpos & 7;
        int orig = (2 * c + (ii >> 2)) * 16 + q * 4 + (ii & 3);
        Wb[OFF_W2F + i] = f2b(ff_w2[e * 256 + orig]);
        return;
    }
    i -= 32768;
    {                  // WC, k-permuted (K=128)
        int o = i >> 7, kpos = i & 127;
        int c = kpos >> 5, q = (kpos >> 3) & 3, ii = kpos & 7;
        int orig = (2 * c + (ii >> 2)) * 16 + q * 4 + (ii & 3);
        Wb[OFF_WC + i] = f2b(conv_w[o * 128 + orig]);
    }
}

// ---------------------------------------------------------------------------
// Input prep (unchanged).
// ---------------------------------------------------------------------------
__global__ __launch_bounds__(256) void k_prep_in(
    const float* __restrict__ buf, const float* __restrict__ spa,
    ushort* __restrict__ T, ushort* __restrict__ S)
{
    const int n = blockIdx.x, y = blockIdx.y;
    __shared__ float t0[64][33];
    __shared__ float t1[64][33];
    const int t = threadIdx.x;
    {
        int ch = t >> 2, x8 = (t & 3) * 8;
        const float* p = buf + ((size_t)(ch * BN + n) * LL + y * Lw + x8);
        const float* q = spa + ((size_t)(ch * BN + n) * LL + y * Lw + x8);
        float4 a0 = ((const float4*)p)[0], a1 = ((const float4*)p)[1];
        float4 b0 = ((const float4*)q)[0], b1 = ((const float4*)q)[1];
        float* d0 = &t0[ch][x8];
        float* d1 = &t1[ch][x8];
        d0[0] = a0.x; d0[1] = a0.y; d0[2] = a0.z; d0[3] = a0.w;
        d0[4] = a1.x; d0[5] = a1.y; d0[6] = a1.z; d0[7] = a1.w;
        d1[0] = a0.x + b0.x; d1[1] = a0.y + b0.y; d1[2] = a0.z + b0.z; d1[3] = a0.w + b0.w;
        d1[4] = a1.x + b1.x; d1[5] = a1.y + b1.y; d1[6] = a1.z + b1.z; d1[7] = a1.w + b1.w;
    }
    __syncthreads();
    {
        int x = t >> 3, c8 = (t & 7) * 8;
        union { ushort u[8]; uint4 v; } o0, o1;
#pragma unroll
        for (int j = 0; j < 8; j++) { o0.u[j] = f2b(t0[c8 + j][x]); o1.u[j] = f2b(t1[c8 + j][x]); }
        size_t base = (((size_t)n * Lh + y) * Lw + x) * 64 + c8;
        *(uint4*)(T + base) = o0.v;
        *(uint4*)(S + base) = o1.v;
    }
}

// ---------------------------------------------------------------------------
// Token embed + LN1 + QKV, fused. 1D grid 800, XCD-swizzled -> (n, y).
// Phase A: im2col MFMA; LN1 -> Xs; bf16(tok) -> Vs. Phase B: QKV MFMAs.
// V is stored TRANSPOSED+PERMUTED (VTg[n][h][y][d][xp]) = PV A-operand layout.
// ---------------------------------------------------------------------------
__global__ __launch_bounds__(256) void k_tok_qkv(
    const ushort* __restrict__ T, const ushort* __restrict__ S,
    const ushort* __restrict__ W2, const ushort* __restrict__ WQK,
    const ushort* __restrict__ WV, const float* __restrict__ g1,
    const float* __restrict__ b1, ushort* __restrict__ TOKb,
    ushort* __restrict__ Qh, ushort* __restrict__ Kh, ushort* __restrict__ VTg)
{
    const int bid = blockIdx.x;                       // 800 blocks
    const int idx = (bid & 7) * 100 + (bid >> 3);     // XCD-contiguous chunks
    const int n = idx / 32, y = idx & 31;
    __shared__ ushort At[3 * 34 * 72];
    __shared__ ushort As_[3 * 34 * 72];
    __shared__ ushort Xs[32 * 136];
    __shared__ ushort Vs[32 * 136];
    __shared__ float2 red[32][4];
    const int t = threadIdx.x;
    const uint4 z = make_uint4(0, 0, 0, 0);

    {
        int x = t >> 3, c8 = (t & 7) * 8;
#pragma unroll
        for (int dy = 0; dy < 3; dy++) {
            int yy = y + dy - 1;
            uint4 va = z, vs = z;
            if (yy >= 0 && yy < Lh) {
                size_t gi = (((size_t)n * Lh + yy) * Lw + x) * 64 + c8;
                va = *(const uint4*)(T + gi);
                vs = *(const uint4*)(S + gi);
            }
            *(uint4*)(At + (dy * 34 + x + 1) * 72 + c8) = va;
            *(uint4*)(As_ + (dy * 34 + x + 1) * 72 + c8) = vs;
        }
        if (t < 48) {
            int dy = t / 16, rem = t % 16;
            int colp = (rem >> 3) * 33, c8p = (rem & 7) * 8;
            *(uint4*)(At + (dy * 34 + colp) * 72 + c8p) = z;
            *(uint4*)(As_ + (dy * 34 + colp) * 72 + c8p) = z;
        }
    }
    __syncthreads();

    const int w = t >> 6, lane = t & 63;
    const int col = lane & 15, quad = lane >> 4;
    f32x4 accT[2][2] = {}, accS[2][2] = {};

    for (int tap = 0; tap < 9; tap++) {
        int dy = tap / 3, dx = tap % 3;
#pragma unroll
        for (int cc = 0; cc < 2; cc++) {
            int kg = tap * 64 + cc * 32 + quad * 8;
            short8 b0 = *(const short8*)(W2 + (size_t)(w * 32 + col) * 576 + kg);
            short8 bq = *(const short8*)(W2 + (size_t)(w * 32 + 16 + col) * 576 + kg);
            int abase = (dy * 34 + col + dx) * 72 + cc * 32 + quad * 8;
            short8 aT0 = *(const short8*)(At + abase);
            short8 aT1 = *(const short8*)(At + abase + 16 * 72);
            short8 aS0 = *(const short8*)(As_ + abase);
            short8 aS1 = *(const short8*)(As_ + abase + 16 * 72);
            accT[0][0] = __builtin_amdgcn_mfma_f32_16x16x32_bf16(aT0, b0, accT[0][0], 0, 0, 0);
            accT[0][1] = __builtin_amdgcn_mfma_f32_16x16x32_bf16(aT0, bq, accT[0][1], 0, 0, 0);
            accT[1][0] = __builtin_amdgcn_mfma_f32_16x16x32_bf16(aT1, b0, accT[1][0], 0, 0, 0);
            accT[1][1] = __builtin_amdgcn_mfma_f32_16x16x32_bf16(aT1, bq, accT[1][1], 0, 0, 0);
            accS[0][0] = __builtin_amdgcn_mfma_f32_16x16x32_bf16(aS0, b0, accS[0][0], 0, 0, 0);
            accS[0][1] = __builtin_amdgcn_mfma_f32_16x16x32_bf16(aS0, bq, accS[0][1], 0, 0, 0);
            accS[1][0] = __builtin_amdgcn_mfma_f32_16x16x32_bf16(aS1, b0, accS[1][0], 0, 0, 0);
            accS[1][1] = __builtin_amdgcn_mfma_f32_16x16x32_bf16(aS1, bq, accS[1][1], 0, 0, 0);
        }
    }

    // LN1 partial sums
#pragma unroll
    for (int mi = 0; mi < 2; mi++)
#pragma unroll
        for (int r = 0; r < 4; r++) {
            float a0 = accS[mi][0][r], a1 = accS[mi][1][r];
            float ss = a0 + a1, qq = a0 * a0 + a1 * a1;
#pragma unroll
            for (int m = 1; m < 16; m <<= 1) {
                ss += __shfl_xor(ss, m, 64);
                qq += __shfl_xor(qq, m, 64);
            }
            if (col == 0) red[mi * 16 + quad * 4 + r][w] = make_float2(ss, qq);
        }
    __syncthreads();

    const float ga = g1[w * 32 + col],      ba = b1[w * 32 + col];
    const float gb = g1[w * 32 + 16 + col], bb = b1[w * 32 + 16 + col];
#pragma unroll
    for (int mi = 0; mi < 2; mi++)
#pragma unroll
        for (int r = 0; r < 4; r++) {
            int x = mi * 16 + quad * 4 + r;
            float2 p0 = red[x][0], p1 = red[x][1], p2 = red[x][2], p3 = red[x][3];
            float mean = (p0.x + p1.x + p2.x + p3.x) * (1.f / 128.f);
            float var  = (p0.y + p1.y + p2.y + p3.y) * (1.f / 128.f) - mean * mean;
            float rstd = rsqrtf(var + 1e-5f);
            int e0 = w * 32 + col, e1 = w * 32 + 16 + col;
            Xs[x * 136 + e0] = f2b((accS[mi][0][r] - mean) * rstd * ga + ba);
            Xs[x * 136 + e1] = f2b((accS[mi][1][r] - mean) * rstd * gb + bb);
            Vs[x * 136 + e0] = f2b(accT[mi][0][r]);
            Vs[x * 136 + e1] = f2b(accT[mi][1][r]);
        }
    __syncthreads();

    // phase B: QKV. Wave w -> heads 2w, 2w+1; token tiles j=0,1.
    short8 xb[2][4], xv[2][4];
#pragma unroll
    for (int j = 0; j < 2; j++)
#pragma unroll
        for (int kc = 0; kc < 4; kc++) {
            xb[j][kc] = *(const short8*)(Xs + (j * 16 + col) * 136 + kc * 32 + quad * 8);
            xv[j][kc] = *(const short8*)(Vs + (j * 16 + col) * 136 + kc * 32 + quad * 8);
        }
    f32x4 Q[2][2] = {}, K[2][2] = {}, V[2][2] = {};
#pragma unroll
    for (int hj = 0; hj < 2; hj++) {
        int h = 2 * w + hj;
#pragma unroll
        for (int kc = 0; kc < 4; kc++) {
            short8 aq = *(const short8*)(WQK + (size_t)(h * 16 + col) * 128 + kc * 32 + quad * 8);
            short8 ak = *(const short8*)(WQK + (size_t)(128 + h * 16 + col) * 128 + kc * 32 + quad * 8);
            short8 av = *(const short8*)(WV + (size_t)(h * 16 + col) * 128 + kc * 32 + quad * 8);
#pragma unroll
            for (int j = 0; j < 2; j++) {
                Q[hj][j] = __builtin_amdgcn_mfma_f32_16x16x32_bf16(aq, xb[j][kc], Q[hj][j], 0, 0, 0);
                K[hj][j] = __builtin_amdgcn_mfma_f32_16x16x32_bf16(ak, xb[j][kc], K[hj][j], 0, 0, 0);
                V[hj][j] = __builtin_amdgcn_mfma_f32_16x16x32_bf16(av, xv[j][kc], V[hj][j], 0, 0, 0);
            }
        }
    }
#pragma unroll
    for (int hj = 0; hj < 2; hj++) {
        int h = 2 * w + hj;
        size_t vrow = ((size_t)(n * 8 + h) * 32 + y) * 512;   // VTg row base
#pragma unroll
        for (int j = 0; j < 2; j++) {
            int l = y * 32 + j * 16 + col;
            size_t base = ((size_t)(n * 8 + h) * 1024 + l) * 16 + quad * 4;
            ushort4 oq, ok;
            oq.x = f2b(Q[hj][j][0]); oq.y = f2b(Q[hj][j][1]); oq.z = f2b(Q[hj][j][2]); oq.w = f2b(Q[hj][j][3]);
            ok.x = f2b(K[hj][j][0]); ok.y = f2b(K[hj][j][1]); ok.z = f2b(K[hj][j][2]); ok.w = f2b(K[hj][j][3]);
            *(ushort4*)(Qh + base) = oq;
            *(ushort4*)(Kh + base) = ok;
            // V transposed + permuted: xp = perm(x), d = quad*4+r
            int xp = ((col >> 2) << 3) + (j << 2) + (col & 3);
#pragma unroll
            for (int r = 0; r < 4; r++)
                VTg[vrow + (quad * 4 + r) * 32 + xp] = f2b(V[hj][j][r]);
        }
    }
    // coalesced TOKb write from Vs
#pragma unroll
    for (int k = 0; k < 2; k++) {
        int idx2 = t + k * 256;
        int r = idx2 >> 4, seg = idx2 & 15;
        *(uint4*)(TOKb + ((size_t)((y * 32 + r) * 25 + n)) * 128 + seg * 8) =
            *(const uint4*)(Vs + r * 136 + seg * 8);
    }
}

// ---------------------------------------------------------------------------
// Attention + out_proj + residual + LN2. 1D grid 1600, XCD-swizzled ->
// (n, y, half): 16 queries/block. Wave w = heads {2w,2w+1} (serial). PV
// A-frags load straight from VTg (no LDS staging). C-frags pack as the
// out_proj B-operand (WO pre-permuted).
// ---------------------------------------------------------------------------
__global__ __launch_bounds__(256) void k_attn_oln(
    const ushort* __restrict__ Qh, const ushort* __restrict__ Kh,
    const ushort* __restrict__ VTg, const ushort* __restrict__ WOP,
    const float* __restrict__ g2, const float* __restrict__ b2,
    ushort* __restrict__ TOKb, ushort* __restrict__ XLN2)
{
    __shared__ ushort OX[16 * 136];
    __shared__ ushort Rs[16 * 136];
    __shared__ float2 red[16][4];
    const int bid = blockIdx.x;                       // 1600 blocks
    const int idx = (bid & 7) * 200 + (bid >> 3);     // XCD-contiguous chunks
    const int n = idx / 64, rem = idx & 63;
    const int y = rem >> 1, half = rem & 1;
    const int t = threadIdx.x, w = t >> 6, lane = t & 63;
    const int col = lane & 15, quad = lane >> 4;

    {   // stage residual rows (16 tokens, bf16)
        int r = t >> 4, seg = t & 15;
        *(uint4*)(Rs + r * 136 + seg * 8) =
            *(const uint4*)(TOKb + ((size_t)((y * 32 + half * 16 + r) * 25 + n)) * 128 + seg * 8);
    }

    short8 z8 = {0, 0, 0, 0, 0, 0, 0, 0};
    const int qx = half * 16 + col;
    f32x4 O2[2] = {};
#pragma unroll
    for (int hj = 0; hj < 2; hj++) {
        const int h = 2 * w + hj;
        const size_t base = (size_t)(n * 8 + h) * 1024;
        const size_t vbase = ((size_t)(n * 8 + h) * 32) * 512;

        short8 qf = z8;
        if (quad < 2)
            qf = *(const short8*)(Qh + (base + y * 32 + half * 16 + col) * 16 + quad * 8);

        f32x4 Sc[10] = {};
#pragma unroll
        for (int tt = 0; tt < 10; tt++) {
            int kr = tt >> 1, kx = ((tt & 1) << 4) + col;
            int yyc = min(max(y - 2 + kr, 0), 31);
            short8 kf = z8;
            if (quad < 2)
                kf = *(const short8*)(Kh + (base + yyc * 32 + kx) * 16 + quad * 8);
            Sc[tt] = __builtin_amdgcn_mfma_f32_16x16x32_bf16(kf, qf, Sc[tt], 0, 0, 0);
        }

        // masked softmax over keys (keys spread over quads -> xor 16,32)
        float mx = -1e30f;
#pragma unroll
        for (int tt = 0; tt < 10; tt++) {
            int yy = y - 2 + (tt >> 1);
            bool rok = (yy >= 0) && (yy < 32);
            int kxb = ((tt & 1) << 4) + quad * 4;
#pragma unroll
            for (int r = 0; r < 4; r++) {
                int dd = kxb + r - qx;
                bool ok = rok && ((unsigned)(dd + 2) <= 4u);
                float v = ok ? Sc[tt][r] * 0.25f : -1e30f;
                Sc[tt][r] = v;
                mx = fmaxf(mx, v);
            }
        }
        mx = fmaxf(mx, __shfl_xor(mx, 16, 64));
        mx = fmaxf(mx, __shfl_xor(mx, 32, 64));
        float sum = 0.f;
#pragma unroll
        for (int tt = 0; tt < 10; tt++)
#pragma unroll
            for (int r = 0; r < 4; r++) {
                float p = __expf(Sc[tt][r] - mx);
                Sc[tt][r] = p;
                sum += p;
            }
        sum += __shfl_xor(sum, 16, 64);
        sum += __shfl_xor(sum, 32, 64);
        const float inv = 1.f / sum;

        // PV: A-frags directly from VTg (coalesced 16B/lane)
#pragma unroll
        for (int c = 0; c < 5; c++) {
            int yyc = min(max(y - 2 + c, 0), 31);
            short8 vt = *(const short8*)(VTg + vbase + (size_t)yyc * 512 + col * 32 + quad * 8);
            union { ushort u[8]; short8 s; } pb;
#pragma unroll
            for (int i = 0; i < 8; i++)
                pb.u[i] = f2b(Sc[2 * c + (i >> 2)][i & 3] * inv);
            O2[hj] = __builtin_amdgcn_mfma_f32_16x16x32_bf16(vt, pb.s, O2[hj], 0, 0, 0);
        }
    }

    // pack O (heads 2w,2w+1) -> OX as B-operand k-slice w
    {
        union { ushort u[8]; uint4 v; } pb;
#pragma unroll
        for (int i = 0; i < 8; i++)
            pb.u[i] = f2b(O2[i >> 2][i & 3]);
        *(uint4*)(OX + col * 136 + w * 32 + quad * 8) = pb.v;
    }
    __syncthreads();

    // out_proj: wave w -> e-tiles {2w, 2w+1}
    f32x4 Y[2] = {};
#pragma unroll
    for (int kc = 0; kc < 4; kc++) {
        short8 hb = *(const short8*)(OX + col * 136 + kc * 32 + quad * 8);
#pragma unroll
        for (int jj = 0; jj < 2; jj++) {
            int et = 2 * w + jj;
            short8 a = *(const short8*)(WOP + (size_t)(et * 16 + col) * 128 + kc * 32 + quad * 8);
            Y[jj] = __builtin_amdgcn_mfma_f32_16x16x32_bf16(a, hb, Y[jj], 0, 0, 0);
        }
    }
    // residual + LN2 stats (token = col)
    float sum = 0.f, sq = 0.f;
#pragma unroll
    for (int jj = 0; jj < 2; jj++)
#pragma unroll
        for (int r = 0; r < 4; r++) {
            int e = (2 * w + jj) * 16 + quad * 4 + r;
            float v = Y[jj][r] + b2f(Rs[col * 136 + e]);
            Y[jj][r] = v;
            sum += v; sq += v * v;
        }
    sum += __shfl_xor(sum, 16, 64); sum += __shfl_xor(sum, 32, 64);
    sq  += __shfl_xor(sq, 16, 64);  sq  += __shfl_xor(sq, 32, 64);
    if (quad == 0) red[col][w] = make_float2(sum, sq);
    __syncthreads();

    float2 p0 = red[col][0], p1 = red[col][1], p2 = red[col][2], p3 = red[col][3];
    float mean = (p0.x + p1.x + p2.x + p3.x) * (1.f / 128.f);
    float var  = (p0.y + p1.y + p2.y + p3.y) * (1.f / 128.f) - mean * mean;
    float rstd = rsqrtf(var + 1e-5f);
#pragma unroll
    for (int jj = 0; jj < 2; jj++)
#pragma unroll
        for (int r = 0; r < 4; r++) {
            int e = (2 * w + jj) * 16 + quad * 4 + r;
            float v = Y[jj][r];
            Rs[col * 136 + e] = f2b(v);
            OX[col * 136 + e] = f2b((v - mean) * rstd * g2[e] + b2[e]);
        }
    __syncthreads();

    {   // coalesced writes (16 rows)
        int r = t >> 4, seg = t & 15;
        size_t go = ((size_t)((y * 32 + half * 16 + r) * 25 + n)) * 128 + seg * 8;
        *(uint4*)(TOKb + go) = *(const uint4*)(Rs + r * 136 + seg * 8);
        *(uint4*)(XLN2 + go) = *(const uint4*)(OX + r * 136 + seg * 8);
    }
}

// ---------------------------------------------------------------------------
// Fused FFN+conv (unchanged from R6).
// ---------------------------------------------------------------------------
__global__ __launch_bounds__(256) void k_ffn(
    const ushort* __restrict__ XLN2, const ushort* __restrict__ TOKb,
    const ushort* __restrict__ W1, const ushort* __restrict__ W2P,
    const ushort* __restrict__ WCP, float* __restrict__ out)
{
    __shared__ ushort Xs[16 * 136];
    __shared__ float  Rsp[16 * 132];
    __shared__ ushort Hs[16 * 264];
    __shared__ ushort Ys[16 * 136];
    const int b = blockIdx.x, bn = b % 25, l0 = (b / 25) * 16;
    const int t = threadIdx.x, w = t >> 6, lane = t & 63;
    const int col = lane & 15, quad = lane >> 4;

    {
        int r = t >> 4, seg = t & 15;
        size_t m = (size_t)(l0 + r) * 25 + bn;
        *(uint4*)(Xs + r * 136 + seg * 8) = *(const uint4*)(XLN2 + m * 128 + seg * 8);
        uint4 tb = *(const uint4*)(TOKb + m * 128 + seg * 8);
        float fv[8];
        unpack8(tb, fv);
#pragma unroll
        for (int j = 0; j < 8; j++) {
            int e = seg * 8 + j;
            int c = e >> 5, halfb = (e >> 4) & 1, q = (e >> 2) & 3, r2 = e & 3;
            Rsp[r * 132 + c * 32 + q * 8 + halfb * 4 + r2] = fv[j];
        }
    }
    __syncthreads();

    short8 xb[4];
#pragma unroll
    for (int kc = 0; kc < 4; kc++)
        xb[kc] = *(const short8*)(Xs + col * 136 + kc * 32 + quad * 8);

    f32x4 H[4] = {};
#pragma unroll
    for (int j = 0; j < 4; j++) {
        int ft = 4 * w + j;
#pragma unroll
        for (int kc = 0; kc < 4; kc++) {
            short8 a = *(const short8*)(W1 + (size_t)(ft * 16 + col) * 128 + kc * 32 + quad * 8);
            H[j] = __builtin_amdgcn_mfma_f32_16x16x32_bf16(a, xb[kc], H[j], 0, 0, 0);
        }
    }
#pragma unroll
    for (int cc = 0; cc < 2; cc++) {
        union { ushort u[8]; uint4 v; } pb;
#pragma unroll
        for (int i = 0; i < 8; i++)
            pb.u[i] = f2b(fmaxf(H[2 * cc + (i >> 2)][i & 3], 0.f));
        *(uint4*)(Hs + col * 264 + (2 * w + cc) * 32 + quad * 8) = pb.v;
    }
    __syncthreads();

    f32x4 Y[2] = {};
#pragma unroll
    for (int kc = 0; kc < 8; kc++) {
        short8 hb = *(const short8*)(Hs + col * 264 + kc * 32 + quad * 8);
#pragma unroll
        for (int j = 0; j < 2; j++) {
            int et = 2 * w + j;
            short8 a = *(const short8*)(W2P + (size_t)(et * 16 + col) * 256 + kc * 32 + quad * 8);
            Y[j] = __builtin_amdgcn_mfma_f32_16x16x32_bf16(a, hb, Y[j], 0, 0, 0);
        }
    }
    {
        float4 r0 = *(const float4*)(Rsp + col * 132 + w * 32 + quad * 8);
        float4 r1 = *(const float4*)(Rsp + col * 132 + w * 32 + quad * 8 + 4);
        union { ushort u[8]; uint4 v; } pb;
        pb.u[0] = f2b(Y[0][0] + r0.x); pb.u[1] = f2b(Y[0][1] + r0.y);
        pb.u[2] = f2b(Y[0][2] + r0.z); pb.u[3] = f2b(Y[0][3] + r0.w);
        pb.u[4] = f2b(Y[1][0] + r1.x); pb.u[5] = f2b(Y[1][1] + r1.y);
        pb.u[6] = f2b(Y[1][2] + r1.z); pb.u[7] = f2b(Y[1][3] + r1.w);
        *(uint4*)(Ys + col * 136 + w * 32 + quad * 8) = pb.v;
    }
    __syncthreads();

    f32x4 O = {};
#pragma unroll
    for (int c = 0; c < 4; c++) {
        short8 yb = *(const short8*)(Ys + col * 136 + c * 32 + quad * 8);
        short8 a = *(const short8*)(WCP + (size_t)(w * 16 + col) * 128 + c * 32 + quad * 8);
        O = __builtin_amdgcn_mfma_f32_16x16x32_bf16(a, yb, O, 0, 0, 0);
    }
    const int l = l0 + col;
#pragma unroll
    for (int r2 = 0; r2 < 4; r2++) {
        int o = w * 16 + quad * 4 + r2;
        out[(size_t)(o * 25 + bn) * 1024 + l] = O[r2];
    }
}

// ---------------------------------------------------------------------------
// Launch
// ---------------------------------------------------------------------------
extern "C" void kernel_launch(void* const* d_in, const int* in_sizes, int n_in,
                              void* d_out, int out_size, void* d_ws, size_t ws_size,
                              hipStream_t stream)
{
    const float* buffer   = (const float*)d_in[0];
    const float* spa      = (const float*)d_in[1];
    const float* w_mlp    = (const float*)d_in[2];
    const float* ln1_g    = (const float*)d_in[3];
    const float* ln1_b    = (const float*)d_in[4];
    const float* in_proj  = (const float*)d_in[5];
    const float* out_proj = (const float*)d_in[6];
    const float* ln2_g    = (const float*)d_in[7];
    const float* ln2_b    = (const float*)d_in[8];
    const float* ff_w1    = (const float*)d_in[9];
    const float* ff_w2    = (const float*)d_in[10];
    const float* conv_w   = (const float*)d_in[11];
    float* out = (float*)d_out;

    char* ws = (char*)d_ws;
    ushort* TOKb = (ushort*)(ws);                //  6,553,600 residual bf16
    ushort* XLN2 = (ushort*)(ws + 6553600);      //  6,553,600
    ushort* Qh   = (ushort*)(ws + 13107200);     //  6,553,600 [n][h][l][d]
    ushort* Kh   = (ushort*)(ws + 19660800);     //  6,553,600
    ushort* VTg  = (ushort*)(ws + 26214400);     //  6,553,600 [n][h][y][d][xp]
    ushort* Tbf  = (ushort*)(ws + 32768000);     //  3,276,800
    ushort* Sbf  = (ushort*)(ws + 36044800);     //  3,276,800
    ushort* Wb   = (ushort*)(ws + 39321600);     //    425,984

    k_prep_w<<<dim3((W_TOTAL + 255) / 256), 256, 0, stream>>>(
        w_mlp, in_proj, out_proj, ff_w1, ff_w2, conv_w, Wb);
    k_prep_in<<<dim3(BN, Lh), 256, 0, stream>>>(buffer, spa, Tbf, Sbf);
    k_tok_qkv<<<dim3(800), 256, 0, stream>>>(Tbf, Sbf, Wb + OFF_W2,
                                             Wb + OFF_WQK, Wb + OFF_WV,
                                             ln1_g, ln1_b, TOKb, Qh, Kh, VTg);
    k_attn_oln<<<dim3(1600), 256, 0, stream>>>(Qh, Kh, VTg, Wb + OFF_WO,
                                               ln2_g, ln2_b, TOKb, XLN2);
    k_ffn<<<dim3(1600), 256, 0, stream>>>(XLN2, TOKb, Wb + OFF_W1, Wb + OFF_W2F,
                                          Wb + OFF_WC, out);
}

// Round 8
// 176.167 us; speedup vs baseline: 1.2712x; 1.0407x over previous
//
#include <hip/hip_runtime.h>
#include <math.h>

// SpaTrans on MI355X. R8: 3-launch pipeline.
//  k_prep     = weight cast/permute + input transpose (merged)
//  k_tok_qkv  = token-embed + LN1 + QKV (VTg now written via LDS repack,
//               coalesced; was 16 scalar 2B scatter stores/lane in R7)
//  k_attn_ffn = attention + out_proj + LN2 + ff1 + relu + ff2 + conv
//               (XLN2/TOKb round-trip eliminated; residual in registers)
#define Lh 32
#define Lw 32
#define LL 1024
#define BN 25
#define EE 128
#define CC 64
#define NHD 8
#define DH 16
#define FFD 256
#define MROWS 25600

typedef __attribute__((ext_vector_type(8))) short short8;
typedef __attribute__((ext_vector_type(4))) float f32x4;

__device__ inline ushort f2b(float x) {
    union { float f; unsigned u; } v; v.f = x;
    unsigned r = (v.u + 0x7fffu + ((v.u >> 16) & 1u)) >> 16;
    return (ushort)r;
}
__device__ inline float b2f(ushort u) {
    union { unsigned u; float f; } v; v.u = ((unsigned)u) << 16;
    return v.f;
}

// ---------------------------------------------------------------------------
// Weight layout (ushorts). W2 K-reordered (k'=tap*64+ch). WO/W2F/WC k-PERMUTED
// (kpos=c*32+q*8+i <-> orig k=(2c+(i>>2))*16+q*4+(i&3)). Q rows pre-scaled 0.25.
// ---------------------------------------------------------------------------
#define OFF_W2  0
#define OFF_WQK 73728
#define OFF_WV  106496
#define OFF_WO  122880
#define OFF_W1  139264
#define OFF_W2F 172032
#define OFF_WC  204800
#define W_TOTAL 212992
#define PREPW_BLOCKS 832

// ---------------------------------------------------------------------------
// Merged prep: blocks [0,832) cast/permute weights; blocks [832,1632) do the
// input transpose buf[ch][n][y][x] -> T[n][y][x][ch] bf16, S = bf16(buf+spa).
// ---------------------------------------------------------------------------
__global__ __launch_bounds__(256) void k_prep(
    const float* __restrict__ w_mlp, const float* __restrict__ in_proj,
    const float* __restrict__ out_proj, const float* __restrict__ ff_w1,
    const float* __restrict__ ff_w2, const float* __restrict__ conv_w,
    const float* __restrict__ buf, const float* __restrict__ spa,
    ushort* __restrict__ Wb, ushort* __restrict__ T, ushort* __restrict__ S)
{
    __shared__ float t0[64][33];
    __shared__ float t1[64][33];
    const int t = threadIdx.x;
    if (blockIdx.x < PREPW_BLOCKS) {
        int i = blockIdx.x * 256 + t;
        if (i >= W_TOTAL) return;
        if (i < 73728) {
            int e = i / 576, k = i - e * 576;
            int tap = k >> 6, ch = k & 63;
            Wb[OFF_W2 + i] = f2b(w_mlp[e * 576 + ch * 9 + tap]);
            return;
        }
        i -= 73728;
        if (i < 32768) {   // WQK; Q rows (first 128) pre-scaled by 1/sqrt(16)
            float v = in_proj[i];
            Wb[OFF_WQK + i] = f2b(i < 16384 ? v * 0.25f : v);
            return;
        }
        i -= 32768;
        if (i < 16384) { Wb[OFF_WV + i] = f2b(in_proj[32768 + i]); return; }
        i -= 16384;
        if (i < 16384) {   // WO, k-permuted (K=128)
            int e = i >> 7, kpos = i & 127;
            int c = kpos >> 5, q = (kpos >> 3) & 3, ii = kpos & 7;
            int orig = (2 * c + (ii >> 2)) * 16 + q * 4 + (ii & 3);
            Wb[OFF_WO + i] = f2b(out_proj[e * 128 + orig]);
            return;
        }
        i -= 16384;
        if (i < 32768) { Wb[OFF_W1 + i] = f2b(ff_w1[i]); return; }
        i -= 32768;
        if (i < 32768) {   // W2F, k-permuted (K=256)
            int e = i >> 8, kpos = i & 255;
            int c = kpos >> 5, q = (kpos >> 3) & 3, ii = kpos & 7;
            int orig = (2 * c + (ii >> 2)) * 16 + q * 4 + (ii & 3);
            Wb[OFF_W2F + i] = f2b(ff_w2[e * 256 + orig]);
            return;
        }
        i -= 32768;
        {                  // WC, k-permuted (K=128)
            int o = i >> 7, kpos = i & 127;
            int c = kpos >> 5, q = (kpos >> 3) & 3, ii = kpos & 7;
            int orig = (2 * c + (ii >> 2)) * 16 + q * 4 + (ii & 3);
            Wb[OFF_WC + i] = f2b(conv_w[o * 128 + orig]);
        }
        return;
    }
    // ---- input transpose ----
    const int bid = blockIdx.x - PREPW_BLOCKS;
    const int n = bid >> 5, y = bid & 31;
    {
        int ch = t >> 2, x8 = (t & 3) * 8;
        const float* p = buf + ((size_t)(ch * BN + n) * LL + y * Lw + x8);
        const float* q = spa + ((size_t)(ch * BN + n) * LL + y * Lw + x8);
        float4 a0 = ((const float4*)p)[0], a1 = ((const float4*)p)[1];
        float4 b0 = ((const float4*)q)[0], b1 = ((const float4*)q)[1];
        float* d0 = &t0[ch][x8];
        float* d1 = &t1[ch][x8];
        d0[0] = a0.x; d0[1] = a0.y; d0[2] = a0.z; d0[3] = a0.w;
        d0[4] = a1.x; d0[5] = a1.y; d0[6] = a1.z; d0[7] = a1.w;
        d1[0] = a0.x + b0.x; d1[1] = a0.y + b0.y; d1[2] = a0.z + b0.z; d1[3] = a0.w + b0.w;
        d1[4] = a1.x + b1.x; d1[5] = a1.y + b1.y; d1[6] = a1.z + b1.z; d1[7] = a1.w + b1.w;
    }
    __syncthreads();
    {
        int x = t >> 3, c8 = (t & 7) * 8;
        union { ushort u[8]; uint4 v; } o0, o1;
#pragma unroll
        for (int j = 0; j < 8; j++) { o0.u[j] = f2b(t0[c8 + j][x]); o1.u[j] = f2b(t1[c8 + j][x]); }
        size_t base = (((size_t)n * Lh + y) * Lw + x) * 64 + c8;
        *(uint4*)(T + base) = o0.v;
        *(uint4*)(S + base) = o1.v;
    }
}

// ---------------------------------------------------------------------------
// Token embed + LN1 + QKV. Grid 800, XCD-swizzled -> (n, y).
// V stored transposed+permuted VTg[n][h][y][d][xp] via LDS repack (coalesced).
// ---------------------------------------------------------------------------
__global__ __launch_bounds__(256) void k_tok_qkv(
    const ushort* __restrict__ T, const ushort* __restrict__ S,
    const ushort* __restrict__ W2, const ushort* __restrict__ WQK,
    const ushort* __restrict__ WV, const float* __restrict__ g1,
    const float* __restrict__ b1, ushort* __restrict__ TOKb,
    ushort* __restrict__ Qh, ushort* __restrict__ Kh, ushort* __restrict__ VTg)
{
    const int bid = blockIdx.x;                       // 800 blocks
    const int idx = (bid & 7) * 100 + (bid >> 3);     // XCD-contiguous chunks
    const int n = idx / 32, y = idx & 31;
    __shared__ ushort At[3 * 34 * 72];
    __shared__ ushort As_[3 * 34 * 72];
    __shared__ ushort Xs[32 * 136];
    __shared__ ushort Vs[32 * 136];
    __shared__ float2 red[32][4];
    const int t = threadIdx.x;
    const uint4 z = make_uint4(0, 0, 0, 0);

    {
        int x = t >> 3, c8 = (t & 7) * 8;
#pragma unroll
        for (int dy = 0; dy < 3; dy++) {
            int yy = y + dy - 1;
            uint4 va = z, vs = z;
            if (yy >= 0 && yy < Lh) {
                size_t gi = (((size_t)n * Lh + yy) * Lw + x) * 64 + c8;
                va = *(const uint4*)(T + gi);
                vs = *(const uint4*)(S + gi);
            }
            *(uint4*)(At + (dy * 34 + x + 1) * 72 + c8) = va;
            *(uint4*)(As_ + (dy * 34 + x + 1) * 72 + c8) = vs;
        }
        if (t < 48) {
            int dy = t / 16, rem = t % 16;
            int colp = (rem >> 3) * 33, c8p = (rem & 7) * 8;
            *(uint4*)(At + (dy * 34 + colp) * 72 + c8p) = z;
            *(uint4*)(As_ + (dy * 34 + colp) * 72 + c8p) = z;
        }
    }
    __syncthreads();

    const int w = t >> 6, lane = t & 63;
    const int col = lane & 15, quad = lane >> 4;
    f32x4 accT[2][2] = {}, accS[2][2] = {};

    for (int tap = 0; tap < 9; tap++) {
        int dy = tap / 3, dx = tap % 3;
#pragma unroll
        for (int cc = 0; cc < 2; cc++) {
            int kg = tap * 64 + cc * 32 + quad * 8;
            short8 b0 = *(const short8*)(W2 + (size_t)(w * 32 + col) * 576 + kg);
            short8 bq = *(const short8*)(W2 + (size_t)(w * 32 + 16 + col) * 576 + kg);
            int abase = (dy * 34 + col + dx) * 72 + cc * 32 + quad * 8;
            short8 aT0 = *(const short8*)(At + abase);
            short8 aT1 = *(const short8*)(At + abase + 16 * 72);
            short8 aS0 = *(const short8*)(As_ + abase);
            short8 aS1 = *(const short8*)(As_ + abase + 16 * 72);
            accT[0][0] = __builtin_amdgcn_mfma_f32_16x16x32_bf16(aT0, b0, accT[0][0], 0, 0, 0);
            accT[0][1] = __builtin_amdgcn_mfma_f32_16x16x32_bf16(aT0, bq, accT[0][1], 0, 0, 0);
            accT[1][0] = __builtin_amdgcn_mfma_f32_16x16x32_bf16(aT1, b0, accT[1][0], 0, 0, 0);
            accT[1][1] = __builtin_amdgcn_mfma_f32_16x16x32_bf16(aT1, bq, accT[1][1], 0, 0, 0);
            accS[0][0] = __builtin_amdgcn_mfma_f32_16x16x32_bf16(aS0, b0, accS[0][0], 0, 0, 0);
            accS[0][1] = __builtin_amdgcn_mfma_f32_16x16x32_bf16(aS0, bq, accS[0][1], 0, 0, 0);
            accS[1][0] = __builtin_amdgcn_mfma_f32_16x16x32_bf16(aS1, b0, accS[1][0], 0, 0, 0);
            accS[1][1] = __builtin_amdgcn_mfma_f32_16x16x32_bf16(aS1, bq, accS[1][1], 0, 0, 0);
        }
    }

    // LN1 partial sums
#pragma unroll
    for (int mi = 0; mi < 2; mi++)
#pragma unroll
        for (int r = 0; r < 4; r++) {
            float a0 = accS[mi][0][r], a1 = accS[mi][1][r];
            float ss = a0 + a1, qq = a0 * a0 + a1 * a1;
#pragma unroll
            for (int m = 1; m < 16; m <<= 1) {
                ss += __shfl_xor(ss, m, 64);
                qq += __shfl_xor(qq, m, 64);
            }
            if (col == 0) red[mi * 16 + quad * 4 + r][w] = make_float2(ss, qq);
        }
    __syncthreads();

    const float ga = g1[w * 32 + col],      ba = b1[w * 32 + col];
    const float gb = g1[w * 32 + 16 + col], bb = b1[w * 32 + 16 + col];
#pragma unroll
    for (int mi = 0; mi < 2; mi++)
#pragma unroll
        for (int r = 0; r < 4; r++) {
            int x = mi * 16 + quad * 4 + r;
            float2 p0 = red[x][0], p1 = red[x][1], p2 = red[x][2], p3 = red[x][3];
            float mean = (p0.x + p1.x + p2.x + p3.x) * (1.f / 128.f);
            float var  = (p0.y + p1.y + p2.y + p3.y) * (1.f / 128.f) - mean * mean;
            float rstd = rsqrtf(var + 1e-5f);
            int e0 = w * 32 + col, e1 = w * 32 + 16 + col;
            Xs[x * 136 + e0] = f2b((accS[mi][0][r] - mean) * rstd * ga + ba);
            Xs[x * 136 + e1] = f2b((accS[mi][1][r] - mean) * rstd * gb + bb);
            Vs[x * 136 + e0] = f2b(accT[mi][0][r]);
            Vs[x * 136 + e1] = f2b(accT[mi][1][r]);
        }
    __syncthreads();

    // phase B: QKV. Wave w -> heads 2w, 2w+1; token tiles j=0,1.
    short8 xb[2][4], xv[2][4];
#pragma unroll
    for (int j = 0; j < 2; j++)
#pragma unroll
        for (int kc = 0; kc < 4; kc++) {
            xb[j][kc] = *(const short8*)(Xs + (j * 16 + col) * 136 + kc * 32 + quad * 8);
            xv[j][kc] = *(const short8*)(Vs + (j * 16 + col) * 136 + kc * 32 + quad * 8);
        }
    f32x4 Q[2][2] = {}, K[2][2] = {}, V[2][2] = {};
#pragma unroll
    for (int hj = 0; hj < 2; hj++) {
        int h = 2 * w + hj;
#pragma unroll
        for (int kc = 0; kc < 4; kc++) {
            short8 aq = *(const short8*)(WQK + (size_t)(h * 16 + col) * 128 + kc * 32 + quad * 8);
            short8 ak = *(const short8*)(WQK + (size_t)(128 + h * 16 + col) * 128 + kc * 32 + quad * 8);
            short8 av = *(const short8*)(WV + (size_t)(h * 16 + col) * 128 + kc * 32 + quad * 8);
#pragma unroll
            for (int j = 0; j < 2; j++) {
                Q[hj][j] = __builtin_amdgcn_mfma_f32_16x16x32_bf16(aq, xb[j][kc], Q[hj][j], 0, 0, 0);
                K[hj][j] = __builtin_amdgcn_mfma_f32_16x16x32_bf16(ak, xb[j][kc], K[hj][j], 0, 0, 0);
                V[hj][j] = __builtin_amdgcn_mfma_f32_16x16x32_bf16(av, xv[j][kc], V[hj][j], 0, 0, 0);
            }
        }
    }
    // Q/K coalesced stores; V -> LDS repack (reuse At: dead after MFMA loop)
    ushort* VTs = At;   // [8 heads][16 d][stride 34]
#pragma unroll
    for (int hj = 0; hj < 2; hj++) {
        int h = 2 * w + hj;
#pragma unroll
        for (int j = 0; j < 2; j++) {
            int l = y * 32 + j * 16 + col;
            size_t base = ((size_t)(n * 8 + h) * 1024 + l) * 16 + quad * 4;
            ushort4 oq, ok;
            oq.x = f2b(Q[hj][j][0]); oq.y = f2b(Q[hj][j][1]); oq.z = f2b(Q[hj][j][2]); oq.w = f2b(Q[hj][j][3]);
            ok.x = f2b(K[hj][j][0]); ok.y = f2b(K[hj][j][1]); ok.z = f2b(K[hj][j][2]); ok.w = f2b(K[hj][j][3]);
            *(ushort4*)(Qh + base) = oq;
            *(ushort4*)(Kh + base) = ok;
            int xp = ((col >> 2) << 3) + (j << 2) + (col & 3);
#pragma unroll
            for (int r = 0; r < 4; r++)
                VTs[(h * 16 + quad * 4 + r) * 34 + xp] = f2b(V[hj][j][r]);
        }
    }
    // coalesced TOKb write from Vs
#pragma unroll
    for (int k = 0; k < 2; k++) {
        int idx2 = t + k * 256;
        int r = idx2 >> 4, seg = idx2 & 15;
        *(uint4*)(TOKb + ((size_t)((y * 32 + r) * 25 + n)) * 128 + seg * 8) =
            *(const uint4*)(Vs + r * 136 + seg * 8);
    }
    __syncthreads();
    {   // coalesced VTg write: 4096 ushorts
        int h = t >> 5, rem = t & 31, d = rem >> 1, xh = (rem & 1) * 16;
        size_t vrow = ((size_t)(n * 8 + h) * 32 + y) * 512;
        union { ushort u[8]; uint4 v; } o0, o1;
#pragma unroll
        for (int j = 0; j < 8; j++) {
            o0.u[j] = VTs[(h * 16 + d) * 34 + xh + j];
            o1.u[j] = VTs[(h * 16 + d) * 34 + xh + 8 + j];
        }
        *(uint4*)(VTg + vrow + d * 32 + xh)     = o0.v;
        *(uint4*)(VTg + vrow + d * 32 + xh + 8) = o1.v;
    }
}

// ---------------------------------------------------------------------------
// Attention + out_proj + residual + LN2 + FFN + conv, fully fused.
// Grid 1600, XCD-swizzled -> (n, y, half): 16 tokens/block.
// Residual carried in REGISTERS between oln and ffn (identical lane mapping).
// ---------------------------------------------------------------------------
__global__ __launch_bounds__(256) void k_attn_ffn(
    const ushort* __restrict__ Qh, const ushort* __restrict__ Kh,
    const ushort* __restrict__ VTg, const ushort* __restrict__ WOP,
    const float* __restrict__ g2, const float* __restrict__ b2,
    const ushort* __restrict__ W1, const ushort* __restrict__ W2P,
    const ushort* __restrict__ WCP, const ushort* __restrict__ TOKb,
    float* __restrict__ out)
{
    __shared__ ushort OX[16 * 136];
    __shared__ ushort Rs[16 * 136];
    __shared__ ushort Hs[16 * 264];
    __shared__ ushort Ys[16 * 136];
    __shared__ float2 red[16][4];
    const int bid = blockIdx.x;                       // 1600 blocks
    const int idx = (bid & 7) * 200 + (bid >> 3);     // XCD-contiguous chunks
    const int n = idx / 64, rem = idx & 63;
    const int y = rem >> 1, half = rem & 1;
    const int l0 = y * 32 + half * 16;
    const int t = threadIdx.x, w = t >> 6, lane = t & 63;
    const int col = lane & 15, quad = lane >> 4;

    {   // stage residual rows (16 tokens, bf16)
        int r = t >> 4, seg = t & 15;
        *(uint4*)(Rs + r * 136 + seg * 8) =
            *(const uint4*)(TOKb + ((size_t)((l0 + r) * 25 + n)) * 128 + seg * 8);
    }

    short8 z8 = {0, 0, 0, 0, 0, 0, 0, 0};
    const int qx = half * 16 + col;
    f32x4 O2[2] = {};
#pragma unroll
    for (int hj = 0; hj < 2; hj++) {
        const int h = 2 * w + hj;
        const size_t base = (size_t)(n * 8 + h) * 1024;
        const size_t vbase = ((size_t)(n * 8 + h) * 32) * 512;

        short8 qf = z8;
        if (quad < 2)
            qf = *(const short8*)(Qh + (base + y * 32 + half * 16 + col) * 16 + quad * 8);

        f32x4 Sc[10] = {};
#pragma unroll
        for (int tt = 0; tt < 10; tt++) {
            int kr = tt >> 1, kx = ((tt & 1) << 4) + col;
            int yyc = min(max(y - 2 + kr, 0), 31);
            short8 kf = z8;
            if (quad < 2)
                kf = *(const short8*)(Kh + (base + yyc * 32 + kx) * 16 + quad * 8);
            Sc[tt] = __builtin_amdgcn_mfma_f32_16x16x32_bf16(kf, qf, Sc[tt], 0, 0, 0);
        }

        // masked softmax over keys (Q pre-scaled; keys spread over quads)
        float mx = -1e30f;
#pragma unroll
        for (int tt = 0; tt < 10; tt++) {
            int yy = y - 2 + (tt >> 1);
            bool rok = (yy >= 0) && (yy < 32);
            int kxb = ((tt & 1) << 4) + quad * 4;
#pragma unroll
            for (int r = 0; r < 4; r++) {
                int dd = kxb + r - qx;
                bool ok = rok && ((unsigned)(dd + 2) <= 4u);
                float v = ok ? Sc[tt][r] : -1e30f;
                Sc[tt][r] = v;
                mx = fmaxf(mx, v);
            }
        }
        mx = fmaxf(mx, __shfl_xor(mx, 16, 64));
        mx = fmaxf(mx, __shfl_xor(mx, 32, 64));
        float sum = 0.f;
#pragma unroll
        for (int tt = 0; tt < 10; tt++)
#pragma unroll
            for (int r = 0; r < 4; r++) {
                float p = __expf(Sc[tt][r] - mx);
                Sc[tt][r] = p;
                sum += p;
            }
        sum += __shfl_xor(sum, 16, 64);
        sum += __shfl_xor(sum, 32, 64);
        const float inv = 1.f / sum;

        // PV: A-frags directly from VTg (coalesced 16B/lane)
#pragma unroll
        for (int c = 0; c < 5; c++) {
            int yyc = min(max(y - 2 + c, 0), 31);
            short8 vt = *(const short8*)(VTg + vbase + (size_t)yyc * 512 + col * 32 + quad * 8);
            union { ushort u[8]; short8 s; } pb;
#pragma unroll
            for (int i = 0; i < 8; i++)
                pb.u[i] = f2b(Sc[2 * c + (i >> 2)][i & 3] * inv);
            O2[hj] = __builtin_amdgcn_mfma_f32_16x16x32_bf16(vt, pb.s, O2[hj], 0, 0, 0);
        }
    }

    // pack O (heads 2w,2w+1) -> OX as B-operand k-slice w
    {
        union { ushort u[8]; uint4 v; } pb;
#pragma unroll
        for (int i = 0; i < 8; i++)
            pb.u[i] = f2b(O2[i >> 2][i & 3]);
        *(uint4*)(OX + col * 136 + w * 32 + quad * 8) = pb.v;
    }
    __syncthreads();

    // out_proj: wave w -> e-tiles {2w, 2w+1}
    f32x4 Y[2] = {};
#pragma unroll
    for (int kc = 0; kc < 4; kc++) {
        short8 hb = *(const short8*)(OX + col * 136 + kc * 32 + quad * 8);
#pragma unroll
        for (int jj = 0; jj < 2; jj++) {
            int et = 2 * w + jj;
            short8 a = *(const short8*)(WOP + (size_t)(et * 16 + col) * 128 + kc * 32 + quad * 8);
            Y[jj] = __builtin_amdgcn_mfma_f32_16x16x32_bf16(a, hb, Y[jj], 0, 0, 0);
        }
    }
    // residual + LN2 stats (token = col); tok2 stays in Y[] registers
    float sum = 0.f, sq = 0.f;
#pragma unroll
    for (int jj = 0; jj < 2; jj++)
#pragma unroll
        for (int r = 0; r < 4; r++) {
            int e = (2 * w + jj) * 16 + quad * 4 + r;
            float v = Y[jj][r] + b2f(Rs[col * 136 + e]);
            Y[jj][r] = v;
            sum += v; sq += v * v;
        }
    sum += __shfl_xor(sum, 16, 64); sum += __shfl_xor(sum, 32, 64);
    sq  += __shfl_xor(sq, 16, 64);  sq  += __shfl_xor(sq, 32, 64);
    if (quad == 0) red[col][w] = make_float2(sum, sq);
    __syncthreads();

    {
        float2 p0 = red[col][0], p1 = red[col][1], p2 = red[col][2], p3 = red[col][3];
        float mean = (p0.x + p1.x + p2.x + p3.x) * (1.f / 128.f);
        float var  = (p0.y + p1.y + p2.y + p3.y) * (1.f / 128.f) - mean * mean;
        float rstd = rsqrtf(var + 1e-5f);
#pragma unroll
        for (int jj = 0; jj < 2; jj++)
#pragma unroll
            for (int r = 0; r < 4; r++) {
                int e = (2 * w + jj) * 16 + quad * 4 + r;
                OX[col * 136 + e] = f2b((Y[jj][r] - mean) * rstd * g2[e] + b2[e]);
            }
    }
    __syncthreads();

    // ffn phase 1: ft = 4w..4w+3 over K=128 from OX (ln2 output)
    short8 xb[4];
#pragma unroll
    for (int kc = 0; kc < 4; kc++)
        xb[kc] = *(const short8*)(OX + col * 136 + kc * 32 + quad * 8);
    f32x4 H[4] = {};
#pragma unroll
    for (int j = 0; j < 4; j++) {
        int ft = 4 * w + j;
#pragma unroll
        for (int kc = 0; kc < 4; kc++) {
            short8 a = *(const short8*)(W1 + (size_t)(ft * 16 + col) * 128 + kc * 32 + quad * 8);
            H[j] = __builtin_amdgcn_mfma_f32_16x16x32_bf16(a, xb[kc], H[j], 0, 0, 0);
        }
    }
#pragma unroll
    for (int cc = 0; cc < 2; cc++) {
        union { ushort u[8]; uint4 v; } pb;
#pragma unroll
        for (int i = 0; i < 8; i++)
            pb.u[i] = f2b(fmaxf(H[2 * cc + (i >> 2)][i & 3], 0.f));
        *(uint4*)(Hs + col * 264 + (2 * w + cc) * 32 + quad * 8) = pb.v;
    }
    __syncthreads();

    // ffn phase 2: et = 2w, 2w+1 over K=256; residual from Y[] registers
    f32x4 Y2[2] = {};
#pragma unroll
    for (int kc = 0; kc < 8; kc++) {
        short8 hb = *(const short8*)(Hs + col * 264 + kc * 32 + quad * 8);
#pragma unroll
        for (int j = 0; j < 2; j++) {
            int et = 2 * w + j;
            short8 a = *(const short8*)(W2P + (size_t)(et * 16 + col) * 256 + kc * 32 + quad * 8);
            Y2[j] = __builtin_amdgcn_mfma_f32_16x16x32_bf16(a, hb, Y2[j], 0, 0, 0);
        }
    }
    {
        union { ushort u[8]; uint4 v; } pb;
#pragma unroll
        for (int i = 0; i < 8; i++)
            pb.u[i] = f2b(Y2[i >> 2][i & 3] + Y[i >> 2][i & 3]);
        *(uint4*)(Ys + col * 136 + w * 32 + quad * 8) = pb.v;
    }
    __syncthreads();

    // ffn phase 3: conv, ot = w
    f32x4 O = {};
#pragma unroll
    for (int c = 0; c < 4; c++) {
        short8 yb = *(const short8*)(Ys + col * 136 + c * 32 + quad * 8);
        short8 a = *(const short8*)(WCP + (size_t)(w * 16 + col) * 128 + c * 32 + quad * 8);
        O = __builtin_amdgcn_mfma_f32_16x16x32_bf16(a, yb, O, 0, 0, 0);
    }
    const int l = l0 + col;
#pragma unroll
    for (int r2 = 0; r2 < 4; r2++) {
        int o = w * 16 + quad * 4 + r2;
        out[(size_t)(o * 25 + n) * 1024 + l] = O[r2];
    }
}

// ---------------------------------------------------------------------------
// Launch
// ---------------------------------------------------------------------------
extern "C" void kernel_launch(void* const* d_in, const int* in_sizes, int n_in,
                              void* d_out, int out_size, void* d_ws, size_t ws_size,
                              hipStream_t stream)
{
    const float* buffer   = (const float*)d_in[0];
    const float* spa      = (const float*)d_in[1];
    const float* w_mlp    = (const float*)d_in[2];
    const float* ln1_g    = (const float*)d_in[3];
    const float* ln1_b    = (const float*)d_in[4];
    const float* in_proj  = (const float*)d_in[5];
    const float* out_proj = (const float*)d_in[6];
    const float* ln2_g    = (const float*)d_in[7];
    const float* ln2_b    = (const float*)d_in[8];
    const float* ff_w1    = (const float*)d_in[9];
    const float* ff_w2    = (const float*)d_in[10];
    const float* conv_w   = (const float*)d_in[11];
    float* out = (float*)d_out;

    char* ws = (char*)d_ws;
    ushort* TOKb = (ushort*)(ws);                //  6,553,600 residual bf16
    ushort* Qh   = (ushort*)(ws + 6553600);      //  6,553,600 [n][h][l][d]
    ushort* Kh   = (ushort*)(ws + 13107200);     //  6,553,600
    ushort* VTg  = (ushort*)(ws + 19660800);     //  6,553,600 [n][h][y][d][xp]
    ushort* Tbf  = (ushort*)(ws + 26214400);     //  3,276,800
    ushort* Sbf  = (ushort*)(ws + 29491200);     //  3,276,800
    ushort* Wb   = (ushort*)(ws + 32768000);     //    425,984

    k_prep<<<dim3(PREPW_BLOCKS + 800), 256, 0, stream>>>(
        w_mlp, in_proj, out_proj, ff_w1, ff_w2, conv_w,
        buffer, spa, Wb, Tbf, Sbf);
    k_tok_qkv<<<dim3(800), 256, 0, stream>>>(Tbf, Sbf, Wb + OFF_W2,
                                             Wb + OFF_WQK, Wb + OFF_WV,
                                             ln1_g, ln1_b, TOKb, Qh, Kh, VTg);
    k_attn_ffn<<<dim3(1600), 256, 0, stream>>>(Qh, Kh, VTg, Wb + OFF_WO,
                                               ln2_g, ln2_b, Wb + OFF_W1,
                                               Wb + OFF_W2F, Wb + OFF_WC,
                                               TOKb, out);
}